// Round 5
// baseline (2684.122 us; speedup 1.0000x reference)
//
#include <hip/hip_runtime.h>
#include <hip/hip_bf16.h>
#include <cstdint>
#include <cstddef>

typedef __hip_bfloat16 bf16;
typedef __attribute__((ext_vector_type(8))) short short8;   // 8 bf16 in 4 VGPRs
typedef __attribute__((ext_vector_type(4))) short short4v;
typedef __attribute__((ext_vector_type(4))) float f32x4;
#define DEVI __device__ __forceinline__

constexpr int Bb = 2, Ll = 6273, Pp = 1568, LL2 = 1569, LP = 1600;
constexpr float QK_SCALE = 0.04419417382415922f;  // 512^-0.5

DEVI short f2bs(float f) {
  __hip_bfloat16 h = __float2bfloat16(f);
  return __builtin_bit_cast(short, h);
}
DEVI float bs2f(short s) {
  __hip_bfloat16 h = __builtin_bit_cast(__hip_bfloat16, s);
  return __bfloat162float(h);
}

// async global->LDS, 16B per lane. LDS dest = wave-uniform base + lane*16.
DEVI void gload16(const short* g, short* l) {
  __builtin_amdgcn_global_load_lds(
      (const __attribute__((address_space(1))) void*)g,
      (__attribute__((address_space(3))) void*)l,
      16, 0, 0);
}

// ===========================================================================
// MFMA tile cores. R3/R4 lesson: double-buffer + source-level vmcnt is
// defeated by the compiler (identical counters) and halves occupancy ->
// keep the PROVEN single-buffer stage -> sync -> mma -> sync schedule (R1,
// 1056us) and raise the ceiling via TILE SIZE instead: 256x256/8-wave for
// the two biggest GEMMs (m230/m248: 2-phase 256^2 = 666-682 TF vs 549 here).
// 16B-slot XOR swizzle (slot ^= row&7) -> conflict-free b128 reads.
// Staging: global_load_lds LINEAR dest + inverse-swizzled per-lane global
// SOURCE (rule 21). C/D layout per m89: col=lane&15, row=quad*4+e.
// ===========================================================================
constexpr int BK = 64;

DEVI int sw_idx(int row, int slot) {            // slot = 16B unit (8 shorts)
  return row * BK + (((slot) ^ (row & 7)) << 3);
}

// 128x128 core: 4 waves in 2x2, per-wave 64x64 (4x4 frags)
DEVI void mma128(const short* As, const short* Bs, int lane, int wr, int wc,
                 f32x4 (&acc)[4][4]) {
  int m = lane & 15, quad = lane >> 4;
  #pragma unroll
  for (int kh = 0; kh < 2; ++kh) {
    int slot = kh * 4 + quad;
    short8 a[4], b[4];
    #pragma unroll
    for (int i = 0; i < 4; ++i) {
      int row = wr * 64 + i * 16 + m;
      a[i] = *(const short8*)(As + sw_idx(row, slot));
    }
    #pragma unroll
    for (int j = 0; j < 4; ++j) {
      int row = wc * 64 + j * 16 + m;
      b[j] = *(const short8*)(Bs + sw_idx(row, slot));
    }
    #pragma unroll
    for (int i = 0; i < 4; ++i)
      #pragma unroll
      for (int j = 0; j < 4; ++j)
        acc[i][j] = __builtin_amdgcn_mfma_f32_16x16x32_bf16(a[i], b[j], acc[i][j], 0, 0, 0);
  }
}

// 256x256 core: 8 waves in 2x4, per-wave 128x64 (8x4 frags, 128 AGPR)
DEVI void mma256(const short* As, const short* Bs, int lane, int wr2, int wc2,
                 f32x4 (&acc)[8][4]) {
  int m = lane & 15, quad = lane >> 4;
  #pragma unroll
  for (int kh = 0; kh < 2; ++kh) {
    int slot = kh * 4 + quad;
    short8 b[4];
    #pragma unroll
    for (int j = 0; j < 4; ++j) {
      int row = wc2 * 64 + j * 16 + m;
      b[j] = *(const short8*)(Bs + sw_idx(row, slot));
    }
    #pragma unroll
    for (int i = 0; i < 8; ++i) {
      int row = wr2 * 128 + i * 16 + m;
      short8 a = *(const short8*)(As + sw_idx(row, slot));
      #pragma unroll
      for (int j = 0; j < 4; ++j)
        acc[i][j] = __builtin_amdgcn_mfma_f32_16x16x32_bf16(a, b[j], acc[i][j], 0, 0, 0);
    }
  }
}

// Old 64x64 core (kept for the small px_pool only)
constexpr int LDT = 40;
DEVI void mma_step(const short* As, const short* Bs, int lane, int wr, int wc,
                   f32x4& c00, f32x4& c01, f32x4& c10, f32x4& c11) {
  int m = lane & 15, quad = lane >> 4;
  const short* a = As + (wr * 32 + m) * LDT + quad * 8;
  const short* b = Bs + (wc * 32 + m) * LDT + quad * 8;
  short8 a0 = *(const short8*)a;
  short8 a1 = *(const short8*)(a + 16 * LDT);
  short8 b0 = *(const short8*)b;
  short8 b1 = *(const short8*)(b + 16 * LDT);
  c00 = __builtin_amdgcn_mfma_f32_16x16x32_bf16(a0, b0, c00, 0, 0, 0);
  c01 = __builtin_amdgcn_mfma_f32_16x16x32_bf16(a0, b1, c01, 0, 0, 0);
  c10 = __builtin_amdgcn_mfma_f32_16x16x32_bf16(a1, b0, c10, 0, 0, 0);
  c11 = __builtin_amdgcn_mfma_f32_16x16x32_bf16(a1, b1, c11, 0, 0, 0);
}

// ---------------------------------------------------------------------------
__global__ void emb_kernel(float* __restrict__ embz) {
  int idx = blockIdx.x * 256 + threadIdx.x;
  if (idx >= LP * 512) return;
  int p = idx >> 9, d = idx & 511;
  float v = 0.f;
  if (p > 0 && p < LL2) {
    int pb = p - 1;
    int t = pb / 196, r = pb % 196;
    int h = r / 14, ww = r % 14;
    int pos, j, half;
    if (d < 170)      { pos = t;  j = d;       half = 85; }
    else if (d < 340) { pos = h;  j = d - 170; half = 85; }
    else              { pos = ww; j = d - 340; half = 86; }
    int jj = (j < half) ? j : (j - half);
    float omega = powf(10000.f, -(float)jj / (float)half);
    float ang = (float)pos * omega;
    v = (j < half) ? sinf(ang) : cosf(ang);
  }
  embz[idx] = v;
}

// f32 -> bf16 bulk convert, 4 elements/thread
__global__ void cvt_kernel(const float* __restrict__ src, short* __restrict__ dst, int n4) {
  int idx = blockIdx.x * 256 + threadIdx.x;
  if (idx >= n4) return;
  float4 v = *(const float4*)(src + (size_t)idx * 4);
  short4v o = { f2bs(v.x), f2bs(v.y), f2bs(v.z), f2bs(v.w) };
  *(short4v*)(dst + (size_t)idx * 4) = o;
}

// wpT[n][tap*512+k] = bf16(wp[n*2048 + k*4 + tap])  (works for wpx/wpq/wpk/wpv)
__global__ void wpxt_kernel(const float* __restrict__ wp, short* __restrict__ wpT) {
  int idx = blockIdx.x * 256 + threadIdx.x;
  if (idx >= 512 * 2048) return;
  int n = idx >> 11, rem = idx & 2047, tap = rem >> 9, k = rem & 511;
  wpT[idx] = f2bs(wp[n * 2048 + k * 4 + tap]);
}

// WT[h][k][i] = bf16(W[(h*512+i)*512 + k])
__global__ void tr_w_kernel(const float* __restrict__ W, short* __restrict__ WT) {
  __shared__ float Ws[64][65];
  int i0 = blockIdx.x * 64, k0 = blockIdx.y * 64, h = blockIdx.z;
  int tid = threadIdx.x;
  int r = tid >> 2, c0 = (tid & 3) * 16;
  const float* src = W + ((size_t)(h * 512 + i0 + r)) * 512 + k0 + c0;
  #pragma unroll
  for (int j = 0; j < 16; ++j) Ws[r][c0 + j] = src[j];
  __syncthreads();
  short* dst = WT + ((size_t)(h * 512 + k0 + r)) * 512 + i0 + c0;
  #pragma unroll
  for (int j = 0; j < 16; ++j) dst[j] = f2bs(Ws[c0 + j][r]);
}

// ===========================================================================
// weff128: Weff[(mat*CH+ch)*512+n][tap*512+k] = sum_i wpT[n][tap*512+i]*WT[h][k][i]
// grid (4, 4, 12*CH) — R1 single-buffer schedule
// ===========================================================================
__global__ void weff128(const short* __restrict__ wpqT, const short* __restrict__ wpkT,
                        const short* __restrict__ wpvT,
                        const short* __restrict__ WqT, const short* __restrict__ WkT,
                        const short* __restrict__ WvT,
                        int h0, int CH, short* __restrict__ Weff) {
  __shared__ __align__(16) short As[128 * BK];
  __shared__ __align__(16) short Bs[128 * BK];
  int n0 = blockIdx.x * 128, k0 = blockIdx.y * 128;
  int z = blockIdx.z;
  int mat = z / (4 * CH), rem = z % (4 * CH);
  int ch = rem >> 2, tap = rem & 3;
  const short* wpT = mat == 0 ? wpqT : (mat == 1 ? wpkT : wpvT);
  const short* WT  = mat == 0 ? WqT  : (mat == 1 ? WkT  : WvT);
  int h = h0 + ch;
  int tid = threadIdx.x, lane = tid & 63, w = tid >> 6, wr = w >> 1, wc = w & 1;
  int rbase = tid >> 3;
  int ss = ((tid & 7) ^ (rbase & 7)) << 3;   // pre-swizzled source slot (shorts)
  f32x4 acc[4][4] = {};
  for (int kq = 0; kq < 512; kq += BK) {
    #pragma unroll
    for (int p = 0; p < 4; ++p) {
      int row = rbase + 32 * p;
      gload16(wpT + (size_t)(n0 + row) * 2048 + tap * 512 + kq + ss,
              As + (32 * p + 8 * w) * BK);
      gload16(WT + ((size_t)(h * 512 + k0 + row)) * 512 + kq + ss,
              Bs + (32 * p + 8 * w) * BK);
    }
    __syncthreads();
    mma128(As, Bs, lane, wr, wc, acc);
    __syncthreads();
  }
  int m = lane & 15, quad = lane >> 4;
  size_t base = ((size_t)(mat * CH + ch) * 512) * 2048 + tap * 512;
  #pragma unroll
  for (int i = 0; i < 4; ++i)
    #pragma unroll
    for (int j = 0; j < 4; ++j)
      #pragma unroll
      for (int e = 0; e < 4; ++e) {
        int n = n0 + wr * 64 + i * 16 + quad * 4 + e;
        int k = k0 + wc * 64 + j * 16 + m;
        Weff[base + (size_t)n * 2048 + k] = f2bs(acc[i][j][e]);
      }
}

// beff_all[(mat*CH+ch)][n]
__global__ void beff_fused(const float* __restrict__ bq, const float* __restrict__ bk,
                           const float* __restrict__ bv,
                           const float* __restrict__ wpq, const float* __restrict__ wpk,
                           const float* __restrict__ wpv,
                           int h0, int CH, float* __restrict__ beff) {
  int mat = blockIdx.x, ch = blockIdx.y, tid = threadIdx.x;
  const float* bias = mat == 0 ? bq : (mat == 1 ? bk : bv);
  const float* wp = mat == 0 ? wpq : (mat == 1 ? wpk : wpv);
  for (int n = tid; n < 512; n += 256) {
    float s = 0.f;
    for (int i = 0; i < 512; ++i) {
      float bi = bias[(h0 + ch) * 512 + i];
      const float* w4 = wp + (size_t)n * 2048 + i * 4;
      s += bi * (w4[0] + w4[1] + w4[2] + w4[3]);
    }
    beff[(mat * CH + ch) * 512 + n] = s;
  }
}

// ===========================================================================
// pool256: flattened GEMM M=3328 (13x256; flat = b*1664 + pooled-row),
// N=1536*CH (6*CH x 256), K=2048. 512 threads, 8 waves 2x4, 64KB LDS,
// single-buffer 2-sync schedule. Bijective XCD swizzle (m204), n-major
// chunks so each XCD reuses its B (Weff) slice across 13 m-tiles.
// Batch straddle at flat row 1664 handled per staged row.
// ===========================================================================
__global__ void pool256(const short* __restrict__ xbf, const short* __restrict__ Weff,
                        const float* __restrict__ beff, const float* __restrict__ embz,
                        short* __restrict__ PQ, short* __restrict__ PKf,
                        short* __restrict__ PVt, int CH) {
  int nwg = gridDim.x;                 // 78*CH
  int bid = blockIdx.x;
  int q8 = nwg >> 3, r8 = nwg & 7;
  int xcd = bid & 7, lin = bid >> 3;
  int wgid = (xcd < r8 ? xcd * (q8 + 1) : r8 * (q8 + 1) + (xcd - r8) * q8) + lin;
  int ntile = wgid / 13, mtile = wgid % 13;
  int n0t = ntile * 256;

  __shared__ __align__(16) short As[256 * BK];
  __shared__ __align__(16) short Bs[256 * BK];
  int tid = threadIdx.x, lane = tid & 63, w = tid >> 6;
  int wr2 = w >> 2, wc2 = w & 3;
  int rbase = tid >> 3;                        // 0..63
  int ss = ((tid & 7) ^ (rbase & 7)) << 3;
  // per staged row: batch + pooled-position base (flat row = b*1664 + pb)
  size_t srcA[4];
  #pragma unroll
  for (int p = 0; p < 4; ++p) {
    int flatr = mtile * 256 + rbase + 64 * p;
    int b_r = flatr >= 1664 ? 1 : 0;
    int pb = flatr - b_r * 1664; if (pb > Pp - 1) pb = Pp - 1;
    int t3 = pb / 196, rm = pb % 196, h2 = rm / 14, w2 = rm % 14;
    int l0 = 1 + t3 * 784 + h2 * 56 + w2 * 2;
    srcA[p] = (size_t)b_r * Ll * 512 + (size_t)l0 * 512;
  }

  f32x4 acc[8][4] = {};
  for (int kq = 0; kq < 2048; kq += BK) {
    int tap = kq >> 9, koff = kq & 511;
    int tr = (tap & 1) + (tap >> 1) * 28;      // taprow: {0,1,28,29}
    #pragma unroll
    for (int p = 0; p < 4; ++p) {
      gload16(xbf + srcA[p] + (size_t)tr * 512 + koff + ss,
              As + (64 * p + 8 * w) * BK);
      gload16(Weff + ((size_t)(n0t + rbase + 64 * p)) * 2048 + kq + ss,
              Bs + (64 * p + 8 * w) * BK);
    }
    __syncthreads();
    mma256(As, Bs, lane, wr2, wc2, acc);
    __syncthreads();
  }
  int m = lane & 15, quad = lane >> 4;
  int span = 512 * CH;
  #pragma unroll
  for (int i = 0; i < 8; ++i)
    #pragma unroll
    for (int j = 0; j < 4; ++j)
      #pragma unroll
      for (int e = 0; e < 4; ++e) {
        int flatr = mtile * 256 + wr2 * 128 + i * 16 + quad * 4 + e;
        int b2 = flatr >= 1664 ? 1 : 0;
        int pb = flatr - b2 * 1664;
        if (pb >= Pp) continue;
        int tok = pb + 1;
        int C = n0t + wc2 * 64 + j * 16 + m;
        int mat = C / span;
        int cm = C - mat * span;
        int ch = cm >> 9, n = cm & 511;
        int cg = b2 * CH + ch;
        float val = acc[i][j][e] + beff[mat * span + cm];
        if (mat == 0)      PQ[((size_t)cg * LP + tok) * 512 + n] = f2bs(val);
        else if (mat == 1) PKf[((size_t)cg * LP + tok) * 512 + n] =
                               f2bs(val * QK_SCALE + embz[(size_t)tok * 512 + n]);
        else               PVt[((size_t)cg * 512 + n) * LP + tok] = f2bs(val);
      }
}

// PX pooled GEMM (64-tile; small)
__global__ void px_pool(const short* __restrict__ xbf, const short* __restrict__ wpxT,
                        short* __restrict__ PX) {
  __shared__ short As[64 * LDT];
  __shared__ short Bs[64 * LDT];
  int mt = blockIdx.x % 25, b = blockIdx.x / 25;
  int n0 = blockIdx.y * 64;
  int tid = threadIdx.x, lane = tid & 63, w = tid >> 6, wr = w >> 1, wc = w & 1;
  int sr = tid >> 2, sc = (tid & 3) * 8;
  int mloc = mt * 64 + sr;
  int pb = mloc < Pp ? mloc : (Pp - 1);
  int t3 = pb / 196, rm = pb % 196, h2 = rm / 14, w2 = rm % 14;
  int l0 = 1 + t3 * 784 + h2 * 56 + w2 * 2;
  const short* xb = xbf + (size_t)b * Ll * 512;
  f32x4 acc[2][2] = {};
  for (int kq = 0; kq < 2048; kq += 32) {
    int tap = kq >> 9;
    int lrow = l0 + (tap >> 1) * 28 + (tap & 1);
    *(short8*)(As + sr * LDT + sc) =
        *(const short8*)(xb + (size_t)lrow * 512 + (kq & 511) + sc);
    *(short8*)(Bs + sr * LDT + sc) =
        *(const short8*)(wpxT + (size_t)(n0 + sr) * 2048 + kq + sc);
    __syncthreads();
    mma_step(As, Bs, lane, wr, wc, acc[0][0], acc[0][1], acc[1][0], acc[1][1]);
    __syncthreads();
  }
  int m = lane & 15, quad = lane >> 4;
  #pragma unroll
  for (int ri = 0; ri < 2; ++ri)
    #pragma unroll
    for (int ci = 0; ci < 2; ++ci)
      #pragma unroll
      for (int e = 0; e < 4; ++e) {
        int mrow = mt * 64 + wr * 32 + ri * 16 + quad * 4 + e;
        int tok = mrow + 1; if (tok > LP - 1) tok = LP - 1;
        int n = n0 + wc * 32 + ci * 16 + m;
        PX[((size_t)b * LP + tok) * 512 + n] = f2bs(acc[ri][ci][e]);
      }
}

// cls row (token 0): one wave per output dot product. grid(128, 3, 2CH)
__global__ void cls_fast(const short* __restrict__ xbf,
                         const float* __restrict__ Wq, const float* __restrict__ bq,
                         const float* __restrict__ Wk, const float* __restrict__ bk,
                         const float* __restrict__ Wv, const float* __restrict__ bv,
                         int h0, int CH,
                         short* __restrict__ PQ, short* __restrict__ PKf,
                         short* __restrict__ PVt) {
  int cg = blockIdx.z, mat = blockIdx.y;
  int wv = threadIdx.x >> 6, lane = threadIdx.x & 63;
  int n = blockIdx.x * 4 + wv;
  int b = cg / CH, h = h0 + cg % CH;
  const float* W = mat == 0 ? Wq : (mat == 1 ? Wk : Wv);
  const float* bias = mat == 0 ? bq : (mat == 1 ? bk : bv);
  const short* xr = xbf + (size_t)b * Ll * 512;
  const float* wr = W + ((size_t)(h * 512 + n)) * 512;
  float s = 0.f;
  #pragma unroll
  for (int j = 0; j < 8; ++j) {
    int k = lane * 8 + j;
    s += bs2f(xr[k]) * wr[k];
  }
  #pragma unroll
  for (int off = 32; off; off >>= 1) s += __shfl_down(s, off, 64);
  if (lane == 0) {
    s += bias[h * 512 + n];
    if (mat == 0)      PQ[((size_t)cg * LP) * 512 + n] = f2bs(s);
    else if (mat == 1) PKf[((size_t)cg * LP) * 512 + n] = f2bs(s * QK_SCALE);
    else               PVt[((size_t)cg * 512 + n) * LP] = f2bs(s);
  }
}

// PX cls row
__global__ void pxcls_kernel(const float* __restrict__ x, short* __restrict__ PX) {
  int b = blockIdx.x, n = threadIdx.x;
  PX[(size_t)b * LP * 512 + n] = f2bs(x[(size_t)b * Ll * 512 + n]);
}

// cfx[cg][kt] = dot(PQ[cg,0,:], embz[kt,:])
__global__ void cfix_kernel(const short* __restrict__ PQ, const float* __restrict__ embz,
                            int a0, float* __restrict__ cfx) {
  int cg = a0 + blockIdx.y;
  int wv = threadIdx.x >> 6, lane = threadIdx.x & 63;
  int kt = blockIdx.x * 4 + wv;
  if (kt >= LP) return;
  int ktc = kt < LL2 ? kt : (LL2 - 1);
  const short* q0 = PQ + (size_t)cg * LP * 512;
  const float* e = embz + (size_t)ktc * 512;
  float s = 0.f;
  #pragma unroll
  for (int j = 0; j < 8; ++j) {
    int d = lane * 8 + j;
    s += bs2f(q0[d]) * e[d];
  }
  #pragma unroll
  for (int off = 32; off; off >>= 1) s += __shfl_down(s, off, 64);
  if (lane == 0) cfx[(size_t)cg * LP + kt] = s;
}

// ===========================================================================
// logits256: Lg[z][q][kt] = PQ[cg] . PKf[cg]; row0 -= cfx. grid (7,7,na),
// 512 threads, 256^2 tile, single-buffer 2-sync schedule.
// ===========================================================================
__global__ void logits256(const short* __restrict__ PQ, const short* __restrict__ PKf,
                          const float* __restrict__ cfx, int a0, float* __restrict__ Lg) {
  __shared__ __align__(16) short As[256 * BK];
  __shared__ __align__(16) short Bs[256 * BK];
  int q0 = blockIdx.x * 256, k0 = blockIdx.y * 256, z = blockIdx.z;
  int cg = a0 + z;
  int tid = threadIdx.x, lane = tid & 63, w = tid >> 6;
  int wr2 = w >> 2, wc2 = w & 3;
  int rbase = tid >> 3;
  int ss = ((tid & 7) ^ (rbase & 7)) << 3;
  const short* Aq = PQ + (size_t)cg * LP * 512;
  const short* Bk = PKf + (size_t)cg * LP * 512;
  f32x4 acc[8][4] = {};
  for (int kq = 0; kq < 512; kq += BK) {
    #pragma unroll
    for (int p = 0; p < 4; ++p) {
      int row = rbase + 64 * p;
      int ar = q0 + row; if (ar > LL2 - 1) ar = LL2 - 1;
      int br = k0 + row; if (br > LL2 - 1) br = LL2 - 1;
      gload16(Aq + (size_t)ar * 512 + kq + ss, As + (64 * p + 8 * w) * BK);
      gload16(Bk + (size_t)br * 512 + kq + ss, Bs + (64 * p + 8 * w) * BK);
    }
    __syncthreads();
    mma256(As, Bs, lane, wr2, wc2, acc);
    __syncthreads();
  }
  int m = lane & 15, quad = lane >> 4;
  float* lg = Lg + (size_t)z * LP * LP;
  const float* cf = cfx + (size_t)cg * LP;
  #pragma unroll
  for (int i = 0; i < 8; ++i)
    #pragma unroll
    for (int j = 0; j < 4; ++j)
      #pragma unroll
      for (int e = 0; e < 4; ++e) {
        int q = q0 + wr2 * 128 + i * 16 + quad * 4 + e;
        int kt = k0 + wc2 * 64 + j * 16 + m;
        if (q >= LP || kt >= LP) continue;
        float val = acc[i][j][e];
        if (q == 0) val -= cf[kt];
        lg[(size_t)q * LP + kt] = val;
      }
}

// softmax row (f32) -> bf16 attn in place
__global__ void softmax_kernel(float* __restrict__ Lg) {
  int q = blockIdx.x, z = blockIdx.y;
  float* p = Lg + ((size_t)z * LP + q) * LP;
  __shared__ float buf[LP];
  __shared__ float red[256];
  int tid = threadIdx.x;
  float mx = -1e30f;
  for (int j = tid; j < LL2; j += 256) { float v = p[j]; buf[j] = v; mx = fmaxf(mx, v); }
  red[tid] = mx; __syncthreads();
  for (int s = 128; s; s >>= 1) { if (tid < s) red[tid] = fmaxf(red[tid], red[tid + s]); __syncthreads(); }
  mx = red[0]; __syncthreads();
  float sum = 0.f;
  for (int j = tid; j < LL2; j += 256) { float e = __expf(buf[j] - mx); buf[j] = e; sum += e; }
  red[tid] = sum; __syncthreads();
  for (int s = 128; s; s >>= 1) { if (tid < s) red[tid] += red[tid + s]; __syncthreads(); }
  float inv = 1.f / red[0];
  short* o = (short*)p;
  for (int j = tid; j < LL2; j += 256) o[j] = f2bs(buf[j] * inv);
  for (int j = LL2 + tid; j < LP; j += 256) o[j] = 0;
}

// ===========================================================================
// av128: Outb[gg][q][n] = attn @ PVt + (q==0?1:2)*PQ. grid (13,4,na)
// (kept 128^2: N=512 -> 256^2 would underfill the 256-CU grid)
// ===========================================================================
__global__ void av128(const float* __restrict__ Lg, const short* __restrict__ PVt,
                      const short* __restrict__ PQ, short* __restrict__ Outb,
                      int h0, int CH, int a0) {
  __shared__ __align__(16) short As[128 * BK];
  __shared__ __align__(16) short Bs[128 * BK];
  int q0 = blockIdx.x * 128, n0 = blockIdx.y * 128, z = blockIdx.z;
  int cg = a0 + z;
  int b = cg / CH, gg = b * 8 + h0 + cg % CH;
  int tid = threadIdx.x, lane = tid & 63, w = tid >> 6, wr = w >> 1, wc = w & 1;
  int rbase = tid >> 3;
  int ss = ((tid & 7) ^ (rbase & 7)) << 3;
  const short* Aat = (const short*)(Lg + (size_t)z * LP * LP);  // bf16 rows, stride 2*LP
  const short* Bv = PVt + (size_t)cg * 512 * LP;
  f32x4 acc[4][4] = {};
  for (int kq = 0; kq < LP; kq += BK) {
    #pragma unroll
    for (int p = 0; p < 4; ++p) {
      int row = rbase + 32 * p;
      int ar = q0 + row; if (ar > LP - 1) ar = LP - 1;
      gload16(Aat + (size_t)ar * (2 * LP) + kq + ss, As + (32 * p + 8 * w) * BK);
      gload16(Bv + (size_t)(n0 + row) * LP + kq + ss, Bs + (32 * p + 8 * w) * BK);
    }
    __syncthreads();
    mma128(As, Bs, lane, wr, wc, acc);
    __syncthreads();
  }
  int m = lane & 15, quad = lane >> 4;
  #pragma unroll
  for (int i = 0; i < 4; ++i)
    #pragma unroll
    for (int j = 0; j < 4; ++j)
      #pragma unroll
      for (int e = 0; e < 4; ++e) {
        int q = q0 + wr * 64 + i * 16 + quad * 4 + e;
        if (q >= LL2) continue;
        int n = n0 + wc * 64 + j * 16 + m;
        float res = bs2f(PQ[((size_t)cg * LP + q) * 512 + n]);
        float val = acc[i][j][e] + (q == 0 ? 1.f : 2.f) * res;
        Outb[((size_t)gg * LP + q) * 512 + n] = f2bs(val);
      }
}

// ===========================================================================
// final128: Y = stacked @ Wd^T + bd + PX. grid (25, 4). M=3138 flat (b,q).
// ===========================================================================
__global__ void final128(const short* __restrict__ Outb, const short* __restrict__ WdB,
                         const float* __restrict__ bd, const short* __restrict__ PX,
                         float* __restrict__ Y) {
  __shared__ __align__(16) short As[128 * BK];
  __shared__ __align__(16) short Bs[128 * BK];
  int mf0 = blockIdx.x * 128, n0 = blockIdx.y * 128;
  int tid = threadIdx.x, lane = tid & 63, w = tid >> 6, wr = w >> 1, wc = w & 1;
  int rbase = tid >> 3;
  int ss = ((tid & 7) ^ (rbase & 7)) << 3;
  const int M = Bb * LL2;  // 3138
  int brow[4], qrow[4];
  #pragma unroll
  for (int p = 0; p < 4; ++p) {
    int mf = mf0 + rbase + 32 * p; if (mf > M - 1) mf = M - 1;
    brow[p] = mf / LL2; qrow[p] = mf % LL2;
  }
  f32x4 acc[4][4] = {};
  for (int kq = 0; kq < 4096; kq += BK) {
    int hh = kq >> 9, koff = kq & 511;
    #pragma unroll
    for (int p = 0; p < 4; ++p) {
      int row = rbase + 32 * p;
      gload16(Outb + ((size_t)(brow[p] * 8 + hh) * LP + qrow[p]) * 512 + koff + ss,
              As + (32 * p + 8 * w) * BK);
      gload16(WdB + (size_t)(n0 + row) * 4096 + kq + ss,
              Bs + (32 * p + 8 * w) * BK);
    }
    __syncthreads();
    mma128(As, Bs, lane, wr, wc, acc);
    __syncthreads();
  }
  int m = lane & 15, quad = lane >> 4;
  #pragma unroll
  for (int i = 0; i < 4; ++i)
    #pragma unroll
    for (int j = 0; j < 4; ++j)
      #pragma unroll
      for (int e = 0; e < 4; ++e) {
        int mf = mf0 + wr * 64 + i * 16 + quad * 4 + e;
        if (mf >= M) continue;
        int b2 = mf / LL2, q2 = mf % LL2;
        int dm = n0 + wc * 64 + j * 16 + m;
        float val = acc[i][j][e] + bd[dm] + bs2f(PX[((size_t)b2 * LP + q2) * 512 + dm]);
        Y[(size_t)mf * 512 + dm] = val;
      }
}

// LayerNorm over 512
__global__ void ln_kernel(const float* __restrict__ Y, const float* __restrict__ gamma,
                          const float* __restrict__ beta, float* __restrict__ Outp) {
  int row = blockIdx.x;
  const float* y = Y + (size_t)row * 512;
  __shared__ float red[256];
  int tid = threadIdx.x;
  float v0 = y[tid], v1 = y[tid + 256];
  red[tid] = v0 + v1; __syncthreads();
  for (int s = 128; s; s >>= 1) { if (tid < s) red[tid] += red[tid + s]; __syncthreads(); }
  float mu = red[0] * (1.f / 512.f);
  __syncthreads();
  float d0 = v0 - mu, d1 = v1 - mu;
  red[tid] = d0 * d0 + d1 * d1; __syncthreads();
  for (int s = 128; s; s >>= 1) { if (tid < s) red[tid] += red[tid + s]; __syncthreads(); }
  float rstd = rsqrtf(red[0] * (1.f / 512.f) + 1e-5f);
  float* o = Outp + (size_t)row * 512;
  o[tid]       = d0 * rstd * gamma[tid]       + beta[tid];
  o[tid + 256] = d1 * rstd * gamma[tid + 256] + beta[tid + 256];
}

// ---------------------------------------------------------------------------
extern "C" void kernel_launch(void* const* d_in, const int* in_sizes, int n_in,
                              void* d_out, int out_size, void* d_ws, size_t ws_size,
                              hipStream_t stream) {
  const float* x     = (const float*)d_in[0];
  const float* Wq    = (const float*)d_in[1];
  const float* bq    = (const float*)d_in[2];
  const float* Wk    = (const float*)d_in[3];
  const float* bk    = (const float*)d_in[4];
  const float* Wv    = (const float*)d_in[5];
  const float* bv    = (const float*)d_in[6];
  const float* wpq   = (const float*)d_in[7];
  const float* wpk   = (const float*)d_in[8];
  const float* wpv   = (const float*)d_in[9];
  const float* wpx   = (const float*)d_in[10];
  const float* Wd    = (const float*)d_in[11];
  const float* bd    = (const float*)d_in[12];
  const float* gamma = (const float*)d_in[13];
  const float* beta  = (const float*)d_in[14];
  float* outp = (float*)d_out;

  auto rnd = [](size_t b) { return (b + 255) / 256 * 256; };
  const size_t persist =
      rnd((size_t)LP * 512 * 4) +            // embz
      rnd((size_t)Bb * Ll * 512 * 2) +       // xbf
      4 * rnd((size_t)512 * 2048 * 2) +      // wpxT + wpqT/wpkT/wpvT
      3 * rnd((size_t)8 * 512 * 512 * 2) +   // WqT/WkT/WvT
      rnd((size_t)512 * 4096 * 2) +          // WdB
      rnd((size_t)16 * LP * 512 * 2) +       // Outb
      rnd((size_t)2 * LP * 512 * 2) +        // PX
      rnd((size_t)2 * LL2 * 512 * 4) +       // Y
      rnd((size_t)16 * LP * 4);              // cfx
  auto chpart = [&](int CH) {
    return rnd((size_t)3 * CH * 512 * 2048 * 2) + rnd((size_t)3 * CH * 512 * 4) +
           3 * rnd((size_t)2 * CH * LP * 512 * 2);
  };
  const size_t lgbytes = rnd((size_t)LP * LP * 4);
  int CH = 8;
  while (CH > 1 && persist + chpart(CH) + lgbytes > ws_size) CH >>= 1;
  if (persist + chpart(CH) + lgbytes > ws_size) return;
  int NA = (int)((ws_size - persist - chpart(CH)) / lgbytes);
  if (NA > 2 * CH) NA = 2 * CH;
  int nc = 8 / CH;

  char* w = (char*)d_ws;
  auto alloc = [&](size_t bytes) { char* p = w; w += (bytes + 255) / 256 * 256; return p; };
  float* embz = (float*)alloc((size_t)LP * 512 * 4);
  short* xbf  = (short*)alloc((size_t)Bb * Ll * 512 * 2);
  short* wpxT = (short*)alloc((size_t)512 * 2048 * 2);
  short* wpqT = (short*)alloc((size_t)512 * 2048 * 2);
  short* wpkT = (short*)alloc((size_t)512 * 2048 * 2);
  short* wpvT = (short*)alloc((size_t)512 * 2048 * 2);
  short* WqT  = (short*)alloc((size_t)8 * 512 * 512 * 2);
  short* WkT  = (short*)alloc((size_t)8 * 512 * 512 * 2);
  short* WvT  = (short*)alloc((size_t)8 * 512 * 512 * 2);
  short* WdB  = (short*)alloc((size_t)512 * 4096 * 2);
  short* Outb = (short*)alloc((size_t)16 * LP * 512 * 2);
  short* PX   = (short*)alloc((size_t)2 * LP * 512 * 2);
  float* Y    = (float*)alloc((size_t)2 * LL2 * 512 * 4);
  float* cfx  = (float*)alloc((size_t)16 * LP * 4);
  short* Weff = (short*)alloc((size_t)3 * CH * 512 * 2048 * 2);
  float* beff = (float*)alloc((size_t)3 * CH * 512 * 4);
  short* PQ   = (short*)alloc((size_t)2 * CH * LP * 512 * 2);
  short* PKf  = (short*)alloc((size_t)2 * CH * LP * 512 * 2);
  short* PVt  = (short*)alloc((size_t)2 * CH * LP * 512 * 2);
  float* Lg   = (float*)alloc((size_t)NA * LP * LP * 4);

  dim3 blk(256);
  dim3 blk512(512);
  emb_kernel<<<dim3((LP * 512 + 255) / 256), blk, 0, stream>>>(embz);
  cvt_kernel<<<dim3((Bb * Ll * 512 / 4 + 255) / 256), blk, 0, stream>>>(x, xbf, Bb * Ll * 512 / 4);
  wpxt_kernel<<<dim3(4096), blk, 0, stream>>>(wpx, wpxT);
  wpxt_kernel<<<dim3(4096), blk, 0, stream>>>(wpq, wpqT);
  wpxt_kernel<<<dim3(4096), blk, 0, stream>>>(wpk, wpkT);
  wpxt_kernel<<<dim3(4096), blk, 0, stream>>>(wpv, wpvT);
  tr_w_kernel<<<dim3(8, 8, 8), blk, 0, stream>>>(Wq, WqT);
  tr_w_kernel<<<dim3(8, 8, 8), blk, 0, stream>>>(Wk, WkT);
  tr_w_kernel<<<dim3(8, 8, 8), blk, 0, stream>>>(Wv, WvT);
  cvt_kernel<<<dim3((512 * 4096 / 4 + 255) / 256), blk, 0, stream>>>(Wd, WdB, 512 * 4096 / 4);
  px_pool<<<dim3(50, 8), blk, 0, stream>>>(xbf, wpxT, PX);
  pxcls_kernel<<<dim3(2), dim3(512), 0, stream>>>(x, PX);

  for (int c = 0; c < nc; ++c) {
    int h0 = c * CH;
    weff128<<<dim3(4, 4, 12 * CH), blk, 0, stream>>>(wpqT, wpkT, wpvT, WqT, WkT, WvT,
                                                     h0, CH, Weff);
    beff_fused<<<dim3(3, CH), blk, 0, stream>>>(bq, bk, bv, wpq, wpk, wpv, h0, CH, beff);
    pool256<<<dim3(78 * CH), blk512, 0, stream>>>(xbf, Weff, beff, embz,
                                                  PQ, PKf, PVt, CH);
    cls_fast<<<dim3(128, 3, 2 * CH), blk, 0, stream>>>(xbf, Wq, bq, Wk, bk, Wv, bv,
                                                       h0, CH, PQ, PKf, PVt);
    for (int a0 = 0; a0 < 2 * CH; a0 += NA) {
      int na = (2 * CH - a0) < NA ? (2 * CH - a0) : NA;
      cfix_kernel<<<dim3(400, na), blk, 0, stream>>>(PQ, embz, a0, cfx);
      logits256<<<dim3(7, 7, na), blk512, 0, stream>>>(PQ, PKf, cfx, a0, Lg);
      softmax_kernel<<<dim3(LL2, na), blk, 0, stream>>>(Lg);
      av128<<<dim3(13, 4, na), blk, 0, stream>>>(Lg, PVt, PQ, Outb, h0, CH, a0);
    }
  }

  final128<<<dim3(25, 4), blk, 0, stream>>>(Outb, WdB, bd, PX, Y);
  ln_kernel<<<dim3(Bb * LL2), blk, 0, stream>>>(Y, gamma, beta, outp);
}

// Round 6
// 1908.100 us; speedup vs baseline: 1.4067x; 1.4067x over previous
//
#include <hip/hip_runtime.h>
#include <hip/hip_bf16.h>
#include <cstdint>
#include <cstddef>

typedef __hip_bfloat16 bf16;
typedef __attribute__((ext_vector_type(8))) short short8;   // 8 bf16 in 4 VGPRs
typedef __attribute__((ext_vector_type(4))) short short4v;
typedef __attribute__((ext_vector_type(4))) float f32x4;
#define DEVI __device__ __forceinline__

constexpr int Bb = 2, Ll = 6273, Pp = 1568, LL2 = 1569, LP = 1600;
constexpr float QK_SCALE = 0.04419417382415922f;  // 512^-0.5

DEVI short f2bs(float f) {
  __hip_bfloat16 h = __float2bfloat16(f);
  return __builtin_bit_cast(short, h);
}
DEVI float bs2f(short s) {
  __hip_bfloat16 h = __builtin_bit_cast(__hip_bfloat16, s);
  return __bfloat162float(h);
}

// async global->LDS, 16B per lane. LDS dest = wave-uniform base + lane*16.
DEVI void gload16(const short* g, short* l) {
  __builtin_amdgcn_global_load_lds(
      (const __attribute__((address_space(1))) void*)g,
      (__attribute__((address_space(3))) void*)l,
      16, 0, 0);
}

// ===========================================================================
// 128x128 MFMA tile core, BK=64, 256 threads = 4 waves in 2x2 (each 64x64 via
// 4x4 frags of mfma_f32_16x16x32_bf16). PROVEN schedule (R1, 1056us):
// single-buffer stage -> __syncthreads -> mma -> __syncthreads.
// R3/R4 lesson: dbuf + source-vmcnt is compiler-defeated & halves occupancy.
// R5 lesson: acc[8][4]@512thr scratch-spilled (31x write amplification) —
// stay at two named acc[4][4] (pool128's proven allocation) when widening.
// 16B-slot XOR swizzle (slot ^= row&7) -> conflict-free b128 reads.
// Staging: global_load_lds LINEAR dest + inverse-swizzled per-lane global
// SOURCE (rule 21). C/D layout per m89: col=lane&15, row=quad*4+e.
// ===========================================================================
constexpr int BK = 64;

DEVI int sw_idx(int row, int slot) {            // slot = 16B unit (8 shorts)
  return row * BK + (((slot) ^ (row & 7)) << 3);
}

DEVI void mma128(const short* As, const short* Bs, int lane, int wr, int wc,
                 f32x4 (&acc)[4][4]) {
  int m = lane & 15, quad = lane >> 4;
  #pragma unroll
  for (int kh = 0; kh < 2; ++kh) {
    int slot = kh * 4 + quad;
    short8 a[4], b[4];
    #pragma unroll
    for (int i = 0; i < 4; ++i) {
      int row = wr * 64 + i * 16 + m;
      a[i] = *(const short8*)(As + sw_idx(row, slot));
    }
    #pragma unroll
    for (int j = 0; j < 4; ++j) {
      int row = wc * 64 + j * 16 + m;
      b[j] = *(const short8*)(Bs + sw_idx(row, slot));
    }
    #pragma unroll
    for (int i = 0; i < 4; ++i)
      #pragma unroll
      for (int j = 0; j < 4; ++j)
        acc[i][j] = __builtin_amdgcn_mfma_f32_16x16x32_bf16(a[i], b[j], acc[i][j], 0, 0, 0);
  }
}

// Old 64x64 core (kept for the small px_pool only)
constexpr int LDT = 40;
DEVI void mma_step(const short* As, const short* Bs, int lane, int wr, int wc,
                   f32x4& c00, f32x4& c01, f32x4& c10, f32x4& c11) {
  int m = lane & 15, quad = lane >> 4;
  const short* a = As + (wr * 32 + m) * LDT + quad * 8;
  const short* b = Bs + (wc * 32 + m) * LDT + quad * 8;
  short8 a0 = *(const short8*)a;
  short8 a1 = *(const short8*)(a + 16 * LDT);
  short8 b0 = *(const short8*)b;
  short8 b1 = *(const short8*)(b + 16 * LDT);
  c00 = __builtin_amdgcn_mfma_f32_16x16x32_bf16(a0, b0, c00, 0, 0, 0);
  c01 = __builtin_amdgcn_mfma_f32_16x16x32_bf16(a0, b1, c01, 0, 0, 0);
  c10 = __builtin_amdgcn_mfma_f32_16x16x32_bf16(a1, b0, c10, 0, 0, 0);
  c11 = __builtin_amdgcn_mfma_f32_16x16x32_bf16(a1, b1, c11, 0, 0, 0);
}

// ---------------------------------------------------------------------------
__global__ void emb_kernel(float* __restrict__ embz) {
  int idx = blockIdx.x * 256 + threadIdx.x;
  if (idx >= LP * 512) return;
  int p = idx >> 9, d = idx & 511;
  float v = 0.f;
  if (p > 0 && p < LL2) {
    int pb = p - 1;
    int t = pb / 196, r = pb % 196;
    int h = r / 14, ww = r % 14;
    int pos, j, half;
    if (d < 170)      { pos = t;  j = d;       half = 85; }
    else if (d < 340) { pos = h;  j = d - 170; half = 85; }
    else              { pos = ww; j = d - 340; half = 86; }
    int jj = (j < half) ? j : (j - half);
    float omega = powf(10000.f, -(float)jj / (float)half);
    float ang = (float)pos * omega;
    v = (j < half) ? sinf(ang) : cosf(ang);
  }
  embz[idx] = v;
}

// f32 -> bf16 bulk convert, 4 elements/thread
__global__ void cvt_kernel(const float* __restrict__ src, short* __restrict__ dst, int n4) {
  int idx = blockIdx.x * 256 + threadIdx.x;
  if (idx >= n4) return;
  float4 v = *(const float4*)(src + (size_t)idx * 4);
  short4v o = { f2bs(v.x), f2bs(v.y), f2bs(v.z), f2bs(v.w) };
  *(short4v*)(dst + (size_t)idx * 4) = o;
}

// wpT[n][tap*512+k] = bf16(wp[n*2048 + k*4 + tap])  (works for wpx/wpq/wpk/wpv)
__global__ void wpxt_kernel(const float* __restrict__ wp, short* __restrict__ wpT) {
  int idx = blockIdx.x * 256 + threadIdx.x;
  if (idx >= 512 * 2048) return;
  int n = idx >> 11, rem = idx & 2047, tap = rem >> 9, k = rem & 511;
  wpT[idx] = f2bs(wp[n * 2048 + k * 4 + tap]);
}

// WT[h][k][i] = bf16(W[(h*512+i)*512 + k])
__global__ void tr_w_kernel(const float* __restrict__ W, short* __restrict__ WT) {
  __shared__ float Ws[64][65];
  int i0 = blockIdx.x * 64, k0 = blockIdx.y * 64, h = blockIdx.z;
  int tid = threadIdx.x;
  int r = tid >> 2, c0 = (tid & 3) * 16;
  const float* src = W + ((size_t)(h * 512 + i0 + r)) * 512 + k0 + c0;
  #pragma unroll
  for (int j = 0; j < 16; ++j) Ws[r][c0 + j] = src[j];
  __syncthreads();
  short* dst = WT + ((size_t)(h * 512 + k0 + r)) * 512 + i0 + c0;
  #pragma unroll
  for (int j = 0; j < 16; ++j) dst[j] = f2bs(Ws[c0 + j][r]);
}

// ===========================================================================
// weff128: Weff[(mat*CH+ch)*512+n][tap*512+k] = sum_i wpT[n][tap*512+i]*WT[h][k][i]
// grid (4, 4, 12*CH) — R1 single-buffer schedule
// ===========================================================================
__global__ void weff128(const short* __restrict__ wpqT, const short* __restrict__ wpkT,
                        const short* __restrict__ wpvT,
                        const short* __restrict__ WqT, const short* __restrict__ WkT,
                        const short* __restrict__ WvT,
                        int h0, int CH, short* __restrict__ Weff) {
  __shared__ __align__(16) short As[128 * BK];
  __shared__ __align__(16) short Bs[128 * BK];
  int n0 = blockIdx.x * 128, k0 = blockIdx.y * 128;
  int z = blockIdx.z;
  int mat = z / (4 * CH), rem = z % (4 * CH);
  int ch = rem >> 2, tap = rem & 3;
  const short* wpT = mat == 0 ? wpqT : (mat == 1 ? wpkT : wpvT);
  const short* WT  = mat == 0 ? WqT  : (mat == 1 ? WkT  : WvT);
  int h = h0 + ch;
  int tid = threadIdx.x, lane = tid & 63, w = tid >> 6, wr = w >> 1, wc = w & 1;
  int rbase = tid >> 3;
  int ss = ((tid & 7) ^ (rbase & 7)) << 3;   // pre-swizzled source slot (shorts)
  f32x4 acc[4][4] = {};
  for (int kq = 0; kq < 512; kq += BK) {
    #pragma unroll
    for (int p = 0; p < 4; ++p) {
      int row = rbase + 32 * p;
      gload16(wpT + (size_t)(n0 + row) * 2048 + tap * 512 + kq + ss,
              As + (32 * p + 8 * w) * BK);
      gload16(WT + ((size_t)(h * 512 + k0 + row)) * 512 + kq + ss,
              Bs + (32 * p + 8 * w) * BK);
    }
    __syncthreads();
    mma128(As, Bs, lane, wr, wc, acc);
    __syncthreads();
  }
  int m = lane & 15, quad = lane >> 4;
  size_t base = ((size_t)(mat * CH + ch) * 512) * 2048 + tap * 512;
  #pragma unroll
  for (int i = 0; i < 4; ++i)
    #pragma unroll
    for (int j = 0; j < 4; ++j)
      #pragma unroll
      for (int e = 0; e < 4; ++e) {
        int n = n0 + wr * 64 + i * 16 + quad * 4 + e;
        int k = k0 + wc * 64 + j * 16 + m;
        Weff[base + (size_t)n * 2048 + k] = f2bs(acc[i][j][e]);
      }
}

// beff_all[(mat*CH+ch)][n]
__global__ void beff_fused(const float* __restrict__ bq, const float* __restrict__ bk,
                           const float* __restrict__ bv,
                           const float* __restrict__ wpq, const float* __restrict__ wpk,
                           const float* __restrict__ wpv,
                           int h0, int CH, float* __restrict__ beff) {
  int mat = blockIdx.x, ch = blockIdx.y, tid = threadIdx.x;
  const float* bias = mat == 0 ? bq : (mat == 1 ? bk : bv);
  const float* wp = mat == 0 ? wpq : (mat == 1 ? wpk : wpv);
  for (int n = tid; n < 512; n += 256) {
    float s = 0.f;
    for (int i = 0; i < 512; ++i) {
      float bi = bias[(h0 + ch) * 512 + i];
      const float* w4 = wp + (size_t)n * 2048 + i * 4;
      s += bi * (w4[0] + w4[1] + w4[2] + w4[3]);
    }
    beff[(mat * CH + ch) * 512 + n] = s;
  }
}

// ===========================================================================
// pool128x2: flattened GEMM, one B-tile (128 cols of Weff) shared by TWO
// A-tiles (mb pair) per block -> B staging stream halves vs pool128, MFMA
// per staged byte doubles. 256 threads, LDS 48KB (A0,A1,B), two PROVEN
// acc[4][4] accumulators (R5 lesson: no [8][4]).
// grid 1D: 13 * 12*CH blocks; bijective XCD swizzle (m204), nt-minor so the
// A-pair stays L2-resident per XCD across the nt sweep.
// ===========================================================================
__global__ void pool128x2(const short* __restrict__ xbf, const short* __restrict__ Weff,
                          const float* __restrict__ beff, const float* __restrict__ embz,
                          short* __restrict__ PQ, short* __restrict__ PKf,
                          short* __restrict__ PVt, int CH) {
  int NT = 12 * CH;
  int nwg = 13 * NT;
  int bid = blockIdx.x;
  int q8 = nwg >> 3, r8 = nwg & 7;
  int xcd = bid & 7, lin = bid >> 3;
  int wgid = (xcd < r8 ? xcd * (q8 + 1) : r8 * (q8 + 1) + (xcd - r8) * q8) + lin;
  int nt = wgid % NT, pr = wgid / NT;        // pr in 0..12
  int mb0 = pr * 2, mb1 = pr * 2 + 1;        // two m-tiles share one B-tile
  int mt0 = mb0 % 13, b0 = mb0 / 13;
  int mt1 = mb1 % 13, b1 = mb1 / 13;
  int mat = nt / (4 * CH), ch = (nt >> 2) % CH;
  int n0t = (nt & 3) * 128;

  __shared__ __align__(16) short As0[128 * BK];
  __shared__ __align__(16) short As1[128 * BK];
  __shared__ __align__(16) short Bs[128 * BK];
  int tid = threadIdx.x, lane = tid & 63, w = tid >> 6, wr = w >> 1, wc = w & 1;
  int rbase = tid >> 3;
  int ss = ((tid & 7) ^ (rbase & 7)) << 3;
  // prologue: pooled-position source bases (in shorts) for the staged rows
  int srcA0[4], srcA1[4];
  #pragma unroll
  for (int p = 0; p < 4; ++p) {
    int row = rbase + 32 * p;
    int pb0 = mt0 * 128 + row; if (pb0 > Pp - 1) pb0 = Pp - 1;
    int t3 = pb0 / 196, rm = pb0 % 196, h2 = rm / 14, w2 = rm % 14;
    srcA0[p] = b0 * (Ll * 512) + (1 + t3 * 784 + h2 * 56 + w2 * 2) * 512;
    int pb1 = mt1 * 128 + row; if (pb1 > Pp - 1) pb1 = Pp - 1;
    int t3b = pb1 / 196, rmb = pb1 % 196, h2b = rmb / 14, w2b = rmb % 14;
    srcA1[p] = b1 * (Ll * 512) + (1 + t3b * 784 + h2b * 56 + w2b * 2) * 512;
  }

  f32x4 acc0[4][4] = {};
  f32x4 acc1[4][4] = {};
  for (int kq = 0; kq < 2048; kq += BK) {
    int tap = kq >> 9, koff = kq & 511;
    int tr = ((tap & 1) + (tap >> 1) * 28) * 512;   // taprow {0,1,28,29} in shorts
    #pragma unroll
    for (int p = 0; p < 4; ++p) {
      int row = rbase + 32 * p;
      gload16(xbf + (size_t)(srcA0[p] + tr + koff + ss), As0 + (32 * p + 8 * w) * BK);
      gload16(xbf + (size_t)(srcA1[p] + tr + koff + ss), As1 + (32 * p + 8 * w) * BK);
      gload16(Weff + ((size_t)nt * 128 + row) * 2048 + kq + ss,
              Bs + (32 * p + 8 * w) * BK);
    }
    __syncthreads();
    mma128(As0, Bs, lane, wr, wc, acc0);
    mma128(As1, Bs, lane, wr, wc, acc1);
    __syncthreads();
  }
  int m = lane & 15, quad = lane >> 4;
  auto epi = [&](f32x4 (&acc)[4][4], int mt, int b2) {
    int cg = b2 * CH + ch;
    #pragma unroll
    for (int i = 0; i < 4; ++i)
      #pragma unroll
      for (int j = 0; j < 4; ++j)
        #pragma unroll
        for (int e = 0; e < 4; ++e) {
          int row = wr * 64 + i * 16 + quad * 4 + e;
          int pb = mt * 128 + row;
          if (pb >= Pp) continue;
          int tok = pb + 1;
          int colLocal = wc * 64 + j * 16 + m;
          int n = n0t + colLocal;
          float val = acc[i][j][e] + beff[(mat * CH + ch) * 512 + n];
          if (mat == 0)      PQ[((size_t)cg * LP + tok) * 512 + n] = f2bs(val);
          else if (mat == 1) PKf[((size_t)cg * LP + tok) * 512 + n] =
                                 f2bs(val * QK_SCALE + embz[(size_t)tok * 512 + n]);
          else               PVt[((size_t)cg * 512 + n) * LP + tok] = f2bs(val);
        }
  };
  epi(acc0, mt0, b0);
  epi(acc1, mt1, b1);
}

// PX pooled GEMM (64-tile; small)
__global__ void px_pool(const short* __restrict__ xbf, const short* __restrict__ wpxT,
                        short* __restrict__ PX) {
  __shared__ short As[64 * LDT];
  __shared__ short Bs[64 * LDT];
  int mt = blockIdx.x % 25, b = blockIdx.x / 25;
  int n0 = blockIdx.y * 64;
  int tid = threadIdx.x, lane = tid & 63, w = tid >> 6, wr = w >> 1, wc = w & 1;
  int sr = tid >> 2, sc = (tid & 3) * 8;
  int mloc = mt * 64 + sr;
  int pb = mloc < Pp ? mloc : (Pp - 1);
  int t3 = pb / 196, rm = pb % 196, h2 = rm / 14, w2 = rm % 14;
  int l0 = 1 + t3 * 784 + h2 * 56 + w2 * 2;
  const short* xb = xbf + (size_t)b * Ll * 512;
  f32x4 acc[2][2] = {};
  for (int kq = 0; kq < 2048; kq += 32) {
    int tap = kq >> 9;
    int lrow = l0 + (tap >> 1) * 28 + (tap & 1);
    *(short8*)(As + sr * LDT + sc) =
        *(const short8*)(xb + (size_t)lrow * 512 + (kq & 511) + sc);
    *(short8*)(Bs + sr * LDT + sc) =
        *(const short8*)(wpxT + (size_t)(n0 + sr) * 2048 + kq + sc);
    __syncthreads();
    mma_step(As, Bs, lane, wr, wc, acc[0][0], acc[0][1], acc[1][0], acc[1][1]);
    __syncthreads();
  }
  int m = lane & 15, quad = lane >> 4;
  #pragma unroll
  for (int ri = 0; ri < 2; ++ri)
    #pragma unroll
    for (int ci = 0; ci < 2; ++ci)
      #pragma unroll
      for (int e = 0; e < 4; ++e) {
        int mrow = mt * 64 + wr * 32 + ri * 16 + quad * 4 + e;
        int tok = mrow + 1; if (tok > LP - 1) tok = LP - 1;
        int n = n0 + wc * 32 + ci * 16 + m;
        PX[((size_t)b * LP + tok) * 512 + n] = f2bs(acc[ri][ci][e]);
      }
}

// cls row (token 0): one wave per output dot product. grid(128, 3, 2CH)
__global__ void cls_fast(const short* __restrict__ xbf,
                         const float* __restrict__ Wq, const float* __restrict__ bq,
                         const float* __restrict__ Wk, const float* __restrict__ bk,
                         const float* __restrict__ Wv, const float* __restrict__ bv,
                         int h0, int CH,
                         short* __restrict__ PQ, short* __restrict__ PKf,
                         short* __restrict__ PVt) {
  int cg = blockIdx.z, mat = blockIdx.y;
  int wv = threadIdx.x >> 6, lane = threadIdx.x & 63;
  int n = blockIdx.x * 4 + wv;
  int b = cg / CH, h = h0 + cg % CH;
  const float* W = mat == 0 ? Wq : (mat == 1 ? Wk : Wv);
  const float* bias = mat == 0 ? bq : (mat == 1 ? bk : bv);
  const short* xr = xbf + (size_t)b * Ll * 512;
  const float* wr = W + ((size_t)(h * 512 + n)) * 512;
  float s = 0.f;
  #pragma unroll
  for (int j = 0; j < 8; ++j) {
    int k = lane * 8 + j;
    s += bs2f(xr[k]) * wr[k];
  }
  #pragma unroll
  for (int off = 32; off; off >>= 1) s += __shfl_down(s, off, 64);
  if (lane == 0) {
    s += bias[h * 512 + n];
    if (mat == 0)      PQ[((size_t)cg * LP) * 512 + n] = f2bs(s);
    else if (mat == 1) PKf[((size_t)cg * LP) * 512 + n] = f2bs(s * QK_SCALE);
    else               PVt[((size_t)cg * 512 + n) * LP] = f2bs(s);
  }
}

// PX cls row
__global__ void pxcls_kernel(const float* __restrict__ x, short* __restrict__ PX) {
  int b = blockIdx.x, n = threadIdx.x;
  PX[(size_t)b * LP * 512 + n] = f2bs(x[(size_t)b * Ll * 512 + n]);
}

// cfx[cg][kt] = dot(PQ[cg,0,:], embz[kt,:])
__global__ void cfix_kernel(const short* __restrict__ PQ, const float* __restrict__ embz,
                            int a0, float* __restrict__ cfx) {
  int cg = a0 + blockIdx.y;
  int wv = threadIdx.x >> 6, lane = threadIdx.x & 63;
  int kt = blockIdx.x * 4 + wv;
  if (kt >= LP) return;
  int ktc = kt < LL2 ? kt : (LL2 - 1);
  const short* q0 = PQ + (size_t)cg * LP * 512;
  const float* e = embz + (size_t)ktc * 512;
  float s = 0.f;
  #pragma unroll
  for (int j = 0; j < 8; ++j) {
    int d = lane * 8 + j;
    s += bs2f(q0[d]) * e[d];
  }
  #pragma unroll
  for (int off = 32; off; off >>= 1) s += __shfl_down(s, off, 64);
  if (lane == 0) cfx[(size_t)cg * LP + kt] = s;
}

// ===========================================================================
// logits128: Lg[z][q][kt] = PQ[cg] . PKf[cg]; row0 -= cfx. grid (13,13,na)
// ===========================================================================
__global__ void logits128(const short* __restrict__ PQ, const short* __restrict__ PKf,
                          const float* __restrict__ cfx, int a0, float* __restrict__ Lg) {
  __shared__ __align__(16) short As[128 * BK];
  __shared__ __align__(16) short Bs[128 * BK];
  int q0 = blockIdx.x * 128, k0 = blockIdx.y * 128, z = blockIdx.z;
  int cg = a0 + z;
  int tid = threadIdx.x, lane = tid & 63, w = tid >> 6, wr = w >> 1, wc = w & 1;
  int rbase = tid >> 3;
  int ss = ((tid & 7) ^ (rbase & 7)) << 3;
  const short* Aq = PQ + (size_t)cg * LP * 512;
  const short* Bk = PKf + (size_t)cg * LP * 512;
  f32x4 acc[4][4] = {};
  for (int kq = 0; kq < 512; kq += BK) {
    #pragma unroll
    for (int p = 0; p < 4; ++p) {
      int row = rbase + 32 * p;
      int ar = q0 + row; if (ar > LL2 - 1) ar = LL2 - 1;
      int br = k0 + row; if (br > LL2 - 1) br = LL2 - 1;
      gload16(Aq + (size_t)ar * 512 + kq + ss, As + (32 * p + 8 * w) * BK);
      gload16(Bk + (size_t)br * 512 + kq + ss, Bs + (32 * p + 8 * w) * BK);
    }
    __syncthreads();
    mma128(As, Bs, lane, wr, wc, acc);
    __syncthreads();
  }
  int m = lane & 15, quad = lane >> 4;
  float* lg = Lg + (size_t)z * LP * LP;
  const float* cf = cfx + (size_t)cg * LP;
  #pragma unroll
  for (int i = 0; i < 4; ++i)
    #pragma unroll
    for (int j = 0; j < 4; ++j)
      #pragma unroll
      for (int e = 0; e < 4; ++e) {
        int q = q0 + wr * 64 + i * 16 + quad * 4 + e;
        int kt = k0 + wc * 64 + j * 16 + m;
        if (q >= LP || kt >= LP) continue;
        float val = acc[i][j][e];
        if (q == 0) val -= cf[kt];
        lg[(size_t)q * LP + kt] = val;
      }
}

// softmax row (f32) -> bf16 attn in place
__global__ void softmax_kernel(float* __restrict__ Lg) {
  int q = blockIdx.x, z = blockIdx.y;
  float* p = Lg + ((size_t)z * LP + q) * LP;
  __shared__ float buf[LP];
  __shared__ float red[256];
  int tid = threadIdx.x;
  float mx = -1e30f;
  for (int j = tid; j < LL2; j += 256) { float v = p[j]; buf[j] = v; mx = fmaxf(mx, v); }
  red[tid] = mx; __syncthreads();
  for (int s = 128; s; s >>= 1) { if (tid < s) red[tid] = fmaxf(red[tid], red[tid + s]); __syncthreads(); }
  mx = red[0]; __syncthreads();
  float sum = 0.f;
  for (int j = tid; j < LL2; j += 256) { float e = __expf(buf[j] - mx); buf[j] = e; sum += e; }
  red[tid] = sum; __syncthreads();
  for (int s = 128; s; s >>= 1) { if (tid < s) red[tid] += red[tid + s]; __syncthreads(); }
  float inv = 1.f / red[0];
  short* o = (short*)p;
  for (int j = tid; j < LL2; j += 256) o[j] = f2bs(buf[j] * inv);
  for (int j = LL2 + tid; j < LP; j += 256) o[j] = 0;
}

// ===========================================================================
// av128: Outb[gg][q][n] = attn @ PVt + (q==0?1:2)*PQ. grid (13,4,na)
// ===========================================================================
__global__ void av128(const float* __restrict__ Lg, const short* __restrict__ PVt,
                      const short* __restrict__ PQ, short* __restrict__ Outb,
                      int h0, int CH, int a0) {
  __shared__ __align__(16) short As[128 * BK];
  __shared__ __align__(16) short Bs[128 * BK];
  int q0 = blockIdx.x * 128, n0 = blockIdx.y * 128, z = blockIdx.z;
  int cg = a0 + z;
  int b = cg / CH, gg = b * 8 + h0 + cg % CH;
  int tid = threadIdx.x, lane = tid & 63, w = tid >> 6, wr = w >> 1, wc = w & 1;
  int rbase = tid >> 3;
  int ss = ((tid & 7) ^ (rbase & 7)) << 3;
  const short* Aat = (const short*)(Lg + (size_t)z * LP * LP);  // bf16 rows, stride 2*LP
  const short* Bv = PVt + (size_t)cg * 512 * LP;
  f32x4 acc[4][4] = {};
  for (int kq = 0; kq < LP; kq += BK) {
    #pragma unroll
    for (int p = 0; p < 4; ++p) {
      int row = rbase + 32 * p;
      int ar = q0 + row; if (ar > LP - 1) ar = LP - 1;
      gload16(Aat + (size_t)ar * (2 * LP) + kq + ss, As + (32 * p + 8 * w) * BK);
      gload16(Bv + (size_t)(n0 + row) * LP + kq + ss, Bs + (32 * p + 8 * w) * BK);
    }
    __syncthreads();
    mma128(As, Bs, lane, wr, wc, acc);
    __syncthreads();
  }
  int m = lane & 15, quad = lane >> 4;
  #pragma unroll
  for (int i = 0; i < 4; ++i)
    #pragma unroll
    for (int j = 0; j < 4; ++j)
      #pragma unroll
      for (int e = 0; e < 4; ++e) {
        int q = q0 + wr * 64 + i * 16 + quad * 4 + e;
        if (q >= LL2) continue;
        int n = n0 + wc * 64 + j * 16 + m;
        float res = bs2f(PQ[((size_t)cg * LP + q) * 512 + n]);
        float val = acc[i][j][e] + (q == 0 ? 1.f : 2.f) * res;
        Outb[((size_t)gg * LP + q) * 512 + n] = f2bs(val);
      }
}

// ===========================================================================
// final128: Y = stacked @ Wd^T + bd + PX. grid (25, 4). M=3138 flat (b,q).
// ===========================================================================
__global__ void final128(const short* __restrict__ Outb, const short* __restrict__ WdB,
                         const float* __restrict__ bd, const short* __restrict__ PX,
                         float* __restrict__ Y) {
  __shared__ __align__(16) short As[128 * BK];
  __shared__ __align__(16) short Bs[128 * BK];
  int mf0 = blockIdx.x * 128, n0 = blockIdx.y * 128;
  int tid = threadIdx.x, lane = tid & 63, w = tid >> 6, wr = w >> 1, wc = w & 1;
  int rbase = tid >> 3;
  int ss = ((tid & 7) ^ (rbase & 7)) << 3;
  const int M = Bb * LL2;  // 3138
  int brow[4], qrow[4];
  #pragma unroll
  for (int p = 0; p < 4; ++p) {
    int mf = mf0 + rbase + 32 * p; if (mf > M - 1) mf = M - 1;
    brow[p] = mf / LL2; qrow[p] = mf % LL2;
  }
  f32x4 acc[4][4] = {};
  for (int kq = 0; kq < 4096; kq += BK) {
    int hh = kq >> 9, koff = kq & 511;
    #pragma unroll
    for (int p = 0; p < 4; ++p) {
      int row = rbase + 32 * p;
      gload16(Outb + ((size_t)(brow[p] * 8 + hh) * LP + qrow[p]) * 512 + koff + ss,
              As + (32 * p + 8 * w) * BK);
      gload16(WdB + (size_t)(n0 + row) * 4096 + kq + ss,
              Bs + (32 * p + 8 * w) * BK);
    }
    __syncthreads();
    mma128(As, Bs, lane, wr, wc, acc);
    __syncthreads();
  }
  int m = lane & 15, quad = lane >> 4;
  #pragma unroll
  for (int i = 0; i < 4; ++i)
    #pragma unroll
    for (int j = 0; j < 4; ++j)
      #pragma unroll
      for (int e = 0; e < 4; ++e) {
        int mf = mf0 + wr * 64 + i * 16 + quad * 4 + e;
        if (mf >= M) continue;
        int b2 = mf / LL2, q2 = mf % LL2;
        int dm = n0 + wc * 64 + j * 16 + m;
        float val = acc[i][j][e] + bd[dm] + bs2f(PX[((size_t)b2 * LP + q2) * 512 + dm]);
        Y[(size_t)mf * 512 + dm] = val;
      }
}

// LayerNorm over 512
__global__ void ln_kernel(const float* __restrict__ Y, const float* __restrict__ gamma,
                          const float* __restrict__ beta, float* __restrict__ Outp) {
  int row = blockIdx.x;
  const float* y = Y + (size_t)row * 512;
  __shared__ float red[256];
  int tid = threadIdx.x;
  float v0 = y[tid], v1 = y[tid + 256];
  red[tid] = v0 + v1; __syncthreads();
  for (int s = 128; s; s >>= 1) { if (tid < s) red[tid] += red[tid + s]; __syncthreads(); }
  float mu = red[0] * (1.f / 512.f);
  __syncthreads();
  float d0 = v0 - mu, d1 = v1 - mu;
  red[tid] = d0 * d0 + d1 * d1; __syncthreads();
  for (int s = 128; s; s >>= 1) { if (tid < s) red[tid] += red[tid + s]; __syncthreads(); }
  float rstd = rsqrtf(red[0] * (1.f / 512.f) + 1e-5f);
  float* o = Outp + (size_t)row * 512;
  o[tid]       = d0 * rstd * gamma[tid]       + beta[tid];
  o[tid + 256] = d1 * rstd * gamma[tid + 256] + beta[tid + 256];
}

// ---------------------------------------------------------------------------
extern "C" void kernel_launch(void* const* d_in, const int* in_sizes, int n_in,
                              void* d_out, int out_size, void* d_ws, size_t ws_size,
                              hipStream_t stream) {
  const float* x     = (const float*)d_in[0];
  const float* Wq    = (const float*)d_in[1];
  const float* bq    = (const float*)d_in[2];
  const float* Wk    = (const float*)d_in[3];
  const float* bk    = (const float*)d_in[4];
  const float* Wv    = (const float*)d_in[5];
  const float* bv    = (const float*)d_in[6];
  const float* wpq   = (const float*)d_in[7];
  const float* wpk   = (const float*)d_in[8];
  const float* wpv   = (const float*)d_in[9];
  const float* wpx   = (const float*)d_in[10];
  const float* Wd    = (const float*)d_in[11];
  const float* bd    = (const float*)d_in[12];
  const float* gamma = (const float*)d_in[13];
  const float* beta  = (const float*)d_in[14];
  float* outp = (float*)d_out;

  auto rnd = [](size_t b) { return (b + 255) / 256 * 256; };
  const size_t persist =
      rnd((size_t)LP * 512 * 4) +            // embz
      rnd((size_t)Bb * Ll * 512 * 2) +       // xbf
      4 * rnd((size_t)512 * 2048 * 2) +      // wpxT + wpqT/wpkT/wpvT
      3 * rnd((size_t)8 * 512 * 512 * 2) +   // WqT/WkT/WvT
      rnd((size_t)512 * 4096 * 2) +          // WdB
      rnd((size_t)16 * LP * 512 * 2) +       // Outb
      rnd((size_t)2 * LP * 512 * 2) +        // PX
      rnd((size_t)2 * LL2 * 512 * 4) +       // Y
      rnd((size_t)16 * LP * 4);              // cfx
  auto chpart = [&](int CH) {
    return rnd((size_t)3 * CH * 512 * 2048 * 2) + rnd((size_t)3 * CH * 512 * 4) +
           3 * rnd((size_t)2 * CH * LP * 512 * 2);
  };
  const size_t lgbytes = rnd((size_t)LP * LP * 4);
  int CH = 8;
  while (CH > 1 && persist + chpart(CH) + lgbytes > ws_size) CH >>= 1;
  if (persist + chpart(CH) + lgbytes > ws_size) return;
  int NA = (int)((ws_size - persist - chpart(CH)) / lgbytes);
  if (NA > 2 * CH) NA = 2 * CH;
  int nc = 8 / CH;

  char* w = (char*)d_ws;
  auto alloc = [&](size_t bytes) { char* p = w; w += (bytes + 255) / 256 * 256; return p; };
  float* embz = (float*)alloc((size_t)LP * 512 * 4);
  short* xbf  = (short*)alloc((size_t)Bb * Ll * 512 * 2);
  short* wpxT = (short*)alloc((size_t)512 * 2048 * 2);
  short* wpqT = (short*)alloc((size_t)512 * 2048 * 2);
  short* wpkT = (short*)alloc((size_t)512 * 2048 * 2);
  short* wpvT = (short*)alloc((size_t)512 * 2048 * 2);
  short* WqT  = (short*)alloc((size_t)8 * 512 * 512 * 2);
  short* WkT  = (short*)alloc((size_t)8 * 512 * 512 * 2);
  short* WvT  = (short*)alloc((size_t)8 * 512 * 512 * 2);
  short* WdB  = (short*)alloc((size_t)512 * 4096 * 2);
  short* Outb = (short*)alloc((size_t)16 * LP * 512 * 2);
  short* PX   = (short*)alloc((size_t)2 * LP * 512 * 2);
  float* Y    = (float*)alloc((size_t)2 * LL2 * 512 * 4);
  float* cfx  = (float*)alloc((size_t)16 * LP * 4);
  short* Weff = (short*)alloc((size_t)3 * CH * 512 * 2048 * 2);
  float* beff = (float*)alloc((size_t)3 * CH * 512 * 4);
  short* PQ   = (short*)alloc((size_t)2 * CH * LP * 512 * 2);
  short* PKf  = (short*)alloc((size_t)2 * CH * LP * 512 * 2);
  short* PVt  = (short*)alloc((size_t)2 * CH * LP * 512 * 2);
  float* Lg   = (float*)alloc((size_t)NA * LP * LP * 4);

  dim3 blk(256);
  emb_kernel<<<dim3((LP * 512 + 255) / 256), blk, 0, stream>>>(embz);
  cvt_kernel<<<dim3((Bb * Ll * 512 / 4 + 255) / 256), blk, 0, stream>>>(x, xbf, Bb * Ll * 512 / 4);
  wpxt_kernel<<<dim3(4096), blk, 0, stream>>>(wpx, wpxT);
  wpxt_kernel<<<dim3(4096), blk, 0, stream>>>(wpq, wpqT);
  wpxt_kernel<<<dim3(4096), blk, 0, stream>>>(wpk, wpkT);
  wpxt_kernel<<<dim3(4096), blk, 0, stream>>>(wpv, wpvT);
  tr_w_kernel<<<dim3(8, 8, 8), blk, 0, stream>>>(Wq, WqT);
  tr_w_kernel<<<dim3(8, 8, 8), blk, 0, stream>>>(Wk, WkT);
  tr_w_kernel<<<dim3(8, 8, 8), blk, 0, stream>>>(Wv, WvT);
  cvt_kernel<<<dim3((512 * 4096 / 4 + 255) / 256), blk, 0, stream>>>(Wd, WdB, 512 * 4096 / 4);
  px_pool<<<dim3(50, 8), blk, 0, stream>>>(xbf, wpxT, PX);
  pxcls_kernel<<<dim3(2), dim3(512), 0, stream>>>(x, PX);

  for (int c = 0; c < nc; ++c) {
    int h0 = c * CH;
    weff128<<<dim3(4, 4, 12 * CH), blk, 0, stream>>>(wpqT, wpkT, wpvT, WqT, WkT, WvT,
                                                     h0, CH, Weff);
    beff_fused<<<dim3(3, CH), blk, 0, stream>>>(bq, bk, bv, wpq, wpk, wpv, h0, CH, beff);
    pool128x2<<<dim3(13 * 12 * CH), blk, 0, stream>>>(xbf, Weff, beff, embz,
                                                      PQ, PKf, PVt, CH);
    cls_fast<<<dim3(128, 3, 2 * CH), blk, 0, stream>>>(xbf, Wq, bq, Wk, bk, Wv, bv,
                                                       h0, CH, PQ, PKf, PVt);
    for (int a0 = 0; a0 < 2 * CH; a0 += NA) {
      int na = (2 * CH - a0) < NA ? (2 * CH - a0) : NA;
      cfix_kernel<<<dim3(400, na), blk, 0, stream>>>(PQ, embz, a0, cfx);
      logits128<<<dim3(13, 13, na), blk, 0, stream>>>(PQ, PKf, cfx, a0, Lg);
      softmax_kernel<<<dim3(LL2, na), blk, 0, stream>>>(Lg);
      av128<<<dim3(13, 4, na), blk, 0, stream>>>(Lg, PVt, PQ, Outb, h0, CH, a0);
    }
  }

  final128<<<dim3(25, 4), blk, 0, stream>>>(Outb, WdB, bd, PX, Y);
  ln_kernel<<<dim3(Bb * LL2), blk, 0, stream>>>(Y, gamma, beta, outp);
}

// Round 7
// 1260.334 us; speedup vs baseline: 2.1297x; 1.5140x over previous
//
#include <hip/hip_runtime.h>
#include <hip/hip_bf16.h>
#include <cstdint>
#include <cstddef>

typedef __hip_bfloat16 bf16;
typedef __attribute__((ext_vector_type(8))) short short8;   // 8 bf16 in 4 VGPRs
typedef __attribute__((ext_vector_type(4))) short short4v;
typedef __attribute__((ext_vector_type(4))) float f32x4;
#define DEVI __device__ __forceinline__

constexpr int Bb = 2, Ll = 6273, Pp = 1568, LL2 = 1569, LP = 1600;
constexpr float QK_SCALE = 0.04419417382415922f;  // 512^-0.5

DEVI short f2bs(float f) {
  __hip_bfloat16 h = __float2bfloat16(f);
  return __builtin_bit_cast(short, h);
}
DEVI float bs2f(short s) {
  __hip_bfloat16 h = __builtin_bit_cast(__hip_bfloat16, s);
  return __bfloat162float(h);
}

// async global->LDS, 16B per lane. LDS dest = wave-uniform base + lane*16.
DEVI void gload16(const short* g, short* l) {
  __builtin_amdgcn_global_load_lds(
      (const __attribute__((address_space(1))) void*)g,
      (__attribute__((address_space(3))) void*)l,
      16, 0, 0);
}

// ===========================================================================
// 128x128 MFMA tile core, BK=64, 256 threads = 4 waves in 2x2 (each 64x64 via
// 4x4 frags of mfma_f32_16x16x32_bf16). PROVEN schedule (R1, 1056us):
// single-buffer stage -> __syncthreads -> mma -> __syncthreads.
// R5/R6 lesson (mechanism found): WITHOUT __launch_bounds__, hipcc caps the
// unified VGPR+AGPR budget at 128/wave (assumes 1024-thr blocks, m69) —
// any kernel needing >128 regs (e.g. 2x acc[4][4] = 128 acc floats) spills
// to scratch: VGPR_Count=64, WRITE_SIZE 2.9GB, MfmaUtil 6%. Fix: declare
// __launch_bounds__(256) on the wide-accumulator kernel.
// 16B-slot XOR swizzle (slot ^= row&7) -> conflict-free b128 reads.
// Staging: global_load_lds LINEAR dest + inverse-swizzled per-lane global
// SOURCE (rule 21). C/D layout per m89: col=lane&15, row=quad*4+e.
// ===========================================================================
constexpr int BK = 64;

DEVI int sw_idx(int row, int slot) {            // slot = 16B unit (8 shorts)
  return row * BK + (((slot) ^ (row & 7)) << 3);
}

DEVI void mma128(const short* As, const short* Bs, int lane, int wr, int wc,
                 f32x4 (&acc)[4][4]) {
  int m = lane & 15, quad = lane >> 4;
  #pragma unroll
  for (int kh = 0; kh < 2; ++kh) {
    int slot = kh * 4 + quad;
    short8 a[4], b[4];
    #pragma unroll
    for (int i = 0; i < 4; ++i) {
      int row = wr * 64 + i * 16 + m;
      a[i] = *(const short8*)(As + sw_idx(row, slot));
    }
    #pragma unroll
    for (int j = 0; j < 4; ++j) {
      int row = wc * 64 + j * 16 + m;
      b[j] = *(const short8*)(Bs + sw_idx(row, slot));
    }
    #pragma unroll
    for (int i = 0; i < 4; ++i)
      #pragma unroll
      for (int j = 0; j < 4; ++j)
        acc[i][j] = __builtin_amdgcn_mfma_f32_16x16x32_bf16(a[i], b[j], acc[i][j], 0, 0, 0);
  }
}

// Old 64x64 core (kept for the small px_pool only)
constexpr int LDT = 40;
DEVI void mma_step(const short* As, const short* Bs, int lane, int wr, int wc,
                   f32x4& c00, f32x4& c01, f32x4& c10, f32x4& c11) {
  int m = lane & 15, quad = lane >> 4;
  const short* a = As + (wr * 32 + m) * LDT + quad * 8;
  const short* b = Bs + (wc * 32 + m) * LDT + quad * 8;
  short8 a0 = *(const short8*)a;
  short8 a1 = *(const short8*)(a + 16 * LDT);
  short8 b0 = *(const short8*)b;
  short8 b1 = *(const short8*)(b + 16 * LDT);
  c00 = __builtin_amdgcn_mfma_f32_16x16x32_bf16(a0, b0, c00, 0, 0, 0);
  c01 = __builtin_amdgcn_mfma_f32_16x16x32_bf16(a0, b1, c01, 0, 0, 0);
  c10 = __builtin_amdgcn_mfma_f32_16x16x32_bf16(a1, b0, c10, 0, 0, 0);
  c11 = __builtin_amdgcn_mfma_f32_16x16x32_bf16(a1, b1, c11, 0, 0, 0);
}

// ---------------------------------------------------------------------------
__global__ void emb_kernel(float* __restrict__ embz) {
  int idx = blockIdx.x * 256 + threadIdx.x;
  if (idx >= LP * 512) return;
  int p = idx >> 9, d = idx & 511;
  float v = 0.f;
  if (p > 0 && p < LL2) {
    int pb = p - 1;
    int t = pb / 196, r = pb % 196;
    int h = r / 14, ww = r % 14;
    int pos, j, half;
    if (d < 170)      { pos = t;  j = d;       half = 85; }
    else if (d < 340) { pos = h;  j = d - 170; half = 85; }
    else              { pos = ww; j = d - 340; half = 86; }
    int jj = (j < half) ? j : (j - half);
    float omega = powf(10000.f, -(float)jj / (float)half);
    float ang = (float)pos * omega;
    v = (j < half) ? sinf(ang) : cosf(ang);
  }
  embz[idx] = v;
}

// f32 -> bf16 bulk convert, 4 elements/thread
__global__ void cvt_kernel(const float* __restrict__ src, short* __restrict__ dst, int n4) {
  int idx = blockIdx.x * 256 + threadIdx.x;
  if (idx >= n4) return;
  float4 v = *(const float4*)(src + (size_t)idx * 4);
  short4v o = { f2bs(v.x), f2bs(v.y), f2bs(v.z), f2bs(v.w) };
  *(short4v*)(dst + (size_t)idx * 4) = o;
}

// wpT[n][tap*512+k] = bf16(wp[n*2048 + k*4 + tap])  (works for wpx/wpq/wpk/wpv)
__global__ void wpxt_kernel(const float* __restrict__ wp, short* __restrict__ wpT) {
  int idx = blockIdx.x * 256 + threadIdx.x;
  if (idx >= 512 * 2048) return;
  int n = idx >> 11, rem = idx & 2047, tap = rem >> 9, k = rem & 511;
  wpT[idx] = f2bs(wp[n * 2048 + k * 4 + tap]);
}

// WT[h][k][i] = bf16(W[(h*512+i)*512 + k])
__global__ void tr_w_kernel(const float* __restrict__ W, short* __restrict__ WT) {
  __shared__ float Ws[64][65];
  int i0 = blockIdx.x * 64, k0 = blockIdx.y * 64, h = blockIdx.z;
  int tid = threadIdx.x;
  int r = tid >> 2, c0 = (tid & 3) * 16;
  const float* src = W + ((size_t)(h * 512 + i0 + r)) * 512 + k0 + c0;
  #pragma unroll
  for (int j = 0; j < 16; ++j) Ws[r][c0 + j] = src[j];
  __syncthreads();
  short* dst = WT + ((size_t)(h * 512 + k0 + r)) * 512 + i0 + c0;
  #pragma unroll
  for (int j = 0; j < 16; ++j) dst[j] = f2bs(Ws[c0 + j][r]);
}

// ===========================================================================
// weff128: Weff[(mat*CH+ch)*512+n][tap*512+k] = sum_i wpT[n][tap*512+i]*WT[h][k][i]
// grid (4, 4, 12*CH) — R1 single-buffer schedule
// ===========================================================================
__global__ void weff128(const short* __restrict__ wpqT, const short* __restrict__ wpkT,
                        const short* __restrict__ wpvT,
                        const short* __restrict__ WqT, const short* __restrict__ WkT,
                        const short* __restrict__ WvT,
                        int h0, int CH, short* __restrict__ Weff) {
  __shared__ __align__(16) short As[128 * BK];
  __shared__ __align__(16) short Bs[128 * BK];
  int n0 = blockIdx.x * 128, k0 = blockIdx.y * 128;
  int z = blockIdx.z;
  int mat = z / (4 * CH), rem = z % (4 * CH);
  int ch = rem >> 2, tap = rem & 3;
  const short* wpT = mat == 0 ? wpqT : (mat == 1 ? wpkT : wpvT);
  const short* WT  = mat == 0 ? WqT  : (mat == 1 ? WkT  : WvT);
  int h = h0 + ch;
  int tid = threadIdx.x, lane = tid & 63, w = tid >> 6, wr = w >> 1, wc = w & 1;
  int rbase = tid >> 3;
  int ss = ((tid & 7) ^ (rbase & 7)) << 3;   // pre-swizzled source slot (shorts)
  f32x4 acc[4][4] = {};
  for (int kq = 0; kq < 512; kq += BK) {
    #pragma unroll
    for (int p = 0; p < 4; ++p) {
      int row = rbase + 32 * p;
      gload16(wpT + (size_t)(n0 + row) * 2048 + tap * 512 + kq + ss,
              As + (32 * p + 8 * w) * BK);
      gload16(WT + ((size_t)(h * 512 + k0 + row)) * 512 + kq + ss,
              Bs + (32 * p + 8 * w) * BK);
    }
    __syncthreads();
    mma128(As, Bs, lane, wr, wc, acc);
    __syncthreads();
  }
  int m = lane & 15, quad = lane >> 4;
  size_t base = ((size_t)(mat * CH + ch) * 512) * 2048 + tap * 512;
  #pragma unroll
  for (int i = 0; i < 4; ++i)
    #pragma unroll
    for (int j = 0; j < 4; ++j)
      #pragma unroll
      for (int e = 0; e < 4; ++e) {
        int n = n0 + wr * 64 + i * 16 + quad * 4 + e;
        int k = k0 + wc * 64 + j * 16 + m;
        Weff[base + (size_t)n * 2048 + k] = f2bs(acc[i][j][e]);
      }
}

// beff_all[(mat*CH+ch)][n]
__global__ void beff_fused(const float* __restrict__ bq, const float* __restrict__ bk,
                           const float* __restrict__ bv,
                           const float* __restrict__ wpq, const float* __restrict__ wpk,
                           const float* __restrict__ wpv,
                           int h0, int CH, float* __restrict__ beff) {
  int mat = blockIdx.x, ch = blockIdx.y, tid = threadIdx.x;
  const float* bias = mat == 0 ? bq : (mat == 1 ? bk : bv);
  const float* wp = mat == 0 ? wpq : (mat == 1 ? wpk : wpv);
  for (int n = tid; n < 512; n += 256) {
    float s = 0.f;
    for (int i = 0; i < 512; ++i) {
      float bi = bias[(h0 + ch) * 512 + i];
      const float* w4 = wp + (size_t)n * 2048 + i * 4;
      s += bi * (w4[0] + w4[1] + w4[2] + w4[3]);
    }
    beff[(mat * CH + ch) * 512 + n] = s;
  }
}

// ===========================================================================
// pool128x2: one B-tile (128 Weff cols) shared by TWO A-tiles per block.
// __launch_bounds__(256) lifts the default 128-reg/wave cap (R5/R6 spill fix)
// so both acc[4][4] arrays live in registers (~192 regs/wave, no spill).
// 256 threads, LDS 48KB. grid 13*12*CH, bijective XCD swizzle (m204).
// ===========================================================================
__global__ void __launch_bounds__(256)
pool128x2(const short* __restrict__ xbf, const short* __restrict__ Weff,
          const float* __restrict__ beff, const float* __restrict__ embz,
          short* __restrict__ PQ, short* __restrict__ PKf,
          short* __restrict__ PVt, int CH) {
  int NT = 12 * CH;
  int nwg = 13 * NT;
  int bid = blockIdx.x;
  int q8 = nwg >> 3, r8 = nwg & 7;
  int xcd = bid & 7, lin = bid >> 3;
  int wgid = (xcd < r8 ? xcd * (q8 + 1) : r8 * (q8 + 1) + (xcd - r8) * q8) + lin;
  int nt = wgid % NT, pr = wgid / NT;        // pr in 0..12
  int mb0 = pr * 2, mb1 = pr * 2 + 1;        // two m-tiles share one B-tile
  int mt0 = mb0 % 13, b0 = mb0 / 13;
  int mt1 = mb1 % 13, b1 = mb1 / 13;
  int mat = nt / (4 * CH), ch = (nt >> 2) % CH;
  int n0t = (nt & 3) * 128;

  __shared__ __align__(16) short As0[128 * BK];
  __shared__ __align__(16) short As1[128 * BK];
  __shared__ __align__(16) short Bs[128 * BK];
  int tid = threadIdx.x, lane = tid & 63, w = tid >> 6, wr = w >> 1, wc = w & 1;
  int rbase = tid >> 3;
  int ss = ((tid & 7) ^ (rbase & 7)) << 3;
  // prologue: pooled-position source bases (in shorts) for the staged rows
  int srcA0[4], srcA1[4];
  #pragma unroll
  for (int p = 0; p < 4; ++p) {
    int row = rbase + 32 * p;
    int pb0 = mt0 * 128 + row; if (pb0 > Pp - 1) pb0 = Pp - 1;
    int t3 = pb0 / 196, rm = pb0 % 196, h2 = rm / 14, w2 = rm % 14;
    srcA0[p] = b0 * (Ll * 512) + (1 + t3 * 784 + h2 * 56 + w2 * 2) * 512;
    int pb1 = mt1 * 128 + row; if (pb1 > Pp - 1) pb1 = Pp - 1;
    int t3b = pb1 / 196, rmb = pb1 % 196, h2b = rmb / 14, w2b = rmb % 14;
    srcA1[p] = b1 * (Ll * 512) + (1 + t3b * 784 + h2b * 56 + w2b * 2) * 512;
  }

  f32x4 acc0[4][4] = {};
  f32x4 acc1[4][4] = {};
  for (int kq = 0; kq < 2048; kq += BK) {
    int tap = kq >> 9, koff = kq & 511;
    int tr = ((tap & 1) + (tap >> 1) * 28) * 512;   // taprow {0,1,28,29} in shorts
    #pragma unroll
    for (int p = 0; p < 4; ++p) {
      int row = rbase + 32 * p;
      gload16(xbf + (size_t)(srcA0[p] + tr + koff + ss), As0 + (32 * p + 8 * w) * BK);
      gload16(xbf + (size_t)(srcA1[p] + tr + koff + ss), As1 + (32 * p + 8 * w) * BK);
      gload16(Weff + ((size_t)nt * 128 + row) * 2048 + kq + ss,
              Bs + (32 * p + 8 * w) * BK);
    }
    __syncthreads();
    mma128(As0, Bs, lane, wr, wc, acc0);
    mma128(As1, Bs, lane, wr, wc, acc1);
    __syncthreads();
  }
  int m = lane & 15, quad = lane >> 4;
  int bb = (mat * CH + ch) * 512;
  // epilogue for acc0 (hand-expanded; no by-reference lambda)
  {
    int cg = b0 * CH + ch;
    #pragma unroll
    for (int i = 0; i < 4; ++i)
      #pragma unroll
      for (int j = 0; j < 4; ++j)
        #pragma unroll
        for (int e = 0; e < 4; ++e) {
          int row = wr * 64 + i * 16 + quad * 4 + e;
          int pb = mt0 * 128 + row;
          if (pb >= Pp) continue;
          int tok = pb + 1;
          int n = n0t + wc * 64 + j * 16 + m;
          float val = acc0[i][j][e] + beff[bb + n];
          if (mat == 0)      PQ[((size_t)cg * LP + tok) * 512 + n] = f2bs(val);
          else if (mat == 1) PKf[((size_t)cg * LP + tok) * 512 + n] =
                                 f2bs(val * QK_SCALE + embz[(size_t)tok * 512 + n]);
          else               PVt[((size_t)cg * 512 + n) * LP + tok] = f2bs(val);
        }
  }
  // epilogue for acc1
  {
    int cg = b1 * CH + ch;
    #pragma unroll
    for (int i = 0; i < 4; ++i)
      #pragma unroll
      for (int j = 0; j < 4; ++j)
        #pragma unroll
        for (int e = 0; e < 4; ++e) {
          int row = wr * 64 + i * 16 + quad * 4 + e;
          int pb = mt1 * 128 + row;
          if (pb >= Pp) continue;
          int tok = pb + 1;
          int n = n0t + wc * 64 + j * 16 + m;
          float val = acc1[i][j][e] + beff[bb + n];
          if (mat == 0)      PQ[((size_t)cg * LP + tok) * 512 + n] = f2bs(val);
          else if (mat == 1) PKf[((size_t)cg * LP + tok) * 512 + n] =
                                 f2bs(val * QK_SCALE + embz[(size_t)tok * 512 + n]);
          else               PVt[((size_t)cg * 512 + n) * LP + tok] = f2bs(val);
        }
  }
}

// PX pooled GEMM (64-tile; small)
__global__ void px_pool(const short* __restrict__ xbf, const short* __restrict__ wpxT,
                        short* __restrict__ PX) {
  __shared__ short As[64 * LDT];
  __shared__ short Bs[64 * LDT];
  int mt = blockIdx.x % 25, b = blockIdx.x / 25;
  int n0 = blockIdx.y * 64;
  int tid = threadIdx.x, lane = tid & 63, w = tid >> 6, wr = w >> 1, wc = w & 1;
  int sr = tid >> 2, sc = (tid & 3) * 8;
  int mloc = mt * 64 + sr;
  int pb = mloc < Pp ? mloc : (Pp - 1);
  int t3 = pb / 196, rm = pb % 196, h2 = rm / 14, w2 = rm % 14;
  int l0 = 1 + t3 * 784 + h2 * 56 + w2 * 2;
  const short* xb = xbf + (size_t)b * Ll * 512;
  f32x4 acc[2][2] = {};
  for (int kq = 0; kq < 2048; kq += 32) {
    int tap = kq >> 9;
    int lrow = l0 + (tap >> 1) * 28 + (tap & 1);
    *(short8*)(As + sr * LDT + sc) =
        *(const short8*)(xb + (size_t)lrow * 512 + (kq & 511) + sc);
    *(short8*)(Bs + sr * LDT + sc) =
        *(const short8*)(wpxT + (size_t)(n0 + sr) * 2048 + kq + sc);
    __syncthreads();
    mma_step(As, Bs, lane, wr, wc, acc[0][0], acc[0][1], acc[1][0], acc[1][1]);
    __syncthreads();
  }
  int m = lane & 15, quad = lane >> 4;
  #pragma unroll
  for (int ri = 0; ri < 2; ++ri)
    #pragma unroll
    for (int ci = 0; ci < 2; ++ci)
      #pragma unroll
      for (int e = 0; e < 4; ++e) {
        int mrow = mt * 64 + wr * 32 + ri * 16 + quad * 4 + e;
        int tok = mrow + 1; if (tok > LP - 1) tok = LP - 1;
        int n = n0 + wc * 32 + ci * 16 + m;
        PX[((size_t)b * LP + tok) * 512 + n] = f2bs(acc[ri][ci][e]);
      }
}

// cls row (token 0): one wave per output dot product. grid(128, 3, 2CH)
__global__ void cls_fast(const short* __restrict__ xbf,
                         const float* __restrict__ Wq, const float* __restrict__ bq,
                         const float* __restrict__ Wk, const float* __restrict__ bk,
                         const float* __restrict__ Wv, const float* __restrict__ bv,
                         int h0, int CH,
                         short* __restrict__ PQ, short* __restrict__ PKf,
                         short* __restrict__ PVt) {
  int cg = blockIdx.z, mat = blockIdx.y;
  int wv = threadIdx.x >> 6, lane = threadIdx.x & 63;
  int n = blockIdx.x * 4 + wv;
  int b = cg / CH, h = h0 + cg % CH;
  const float* W = mat == 0 ? Wq : (mat == 1 ? Wk : Wv);
  const float* bias = mat == 0 ? bq : (mat == 1 ? bk : bv);
  const short* xr = xbf + (size_t)b * Ll * 512;
  const float* wr = W + ((size_t)(h * 512 + n)) * 512;
  float s = 0.f;
  #pragma unroll
  for (int j = 0; j < 8; ++j) {
    int k = lane * 8 + j;
    s += bs2f(xr[k]) * wr[k];
  }
  #pragma unroll
  for (int off = 32; off; off >>= 1) s += __shfl_down(s, off, 64);
  if (lane == 0) {
    s += bias[h * 512 + n];
    if (mat == 0)      PQ[((size_t)cg * LP) * 512 + n] = f2bs(s);
    else if (mat == 1) PKf[((size_t)cg * LP) * 512 + n] = f2bs(s * QK_SCALE);
    else               PVt[((size_t)cg * 512 + n) * LP] = f2bs(s);
  }
}

// PX cls row
__global__ void pxcls_kernel(const float* __restrict__ x, short* __restrict__ PX) {
  int b = blockIdx.x, n = threadIdx.x;
  PX[(size_t)b * LP * 512 + n] = f2bs(x[(size_t)b * Ll * 512 + n]);
}

// cfx[cg][kt] = dot(PQ[cg,0,:], embz[kt,:])
__global__ void cfix_kernel(const short* __restrict__ PQ, const float* __restrict__ embz,
                            int a0, float* __restrict__ cfx) {
  int cg = a0 + blockIdx.y;
  int wv = threadIdx.x >> 6, lane = threadIdx.x & 63;
  int kt = blockIdx.x * 4 + wv;
  if (kt >= LP) return;
  int ktc = kt < LL2 ? kt : (LL2 - 1);
  const short* q0 = PQ + (size_t)cg * LP * 512;
  const float* e = embz + (size_t)ktc * 512;
  float s = 0.f;
  #pragma unroll
  for (int j = 0; j < 8; ++j) {
    int d = lane * 8 + j;
    s += bs2f(q0[d]) * e[d];
  }
  #pragma unroll
  for (int off = 32; off; off >>= 1) s += __shfl_down(s, off, 64);
  if (lane == 0) cfx[(size_t)cg * LP + kt] = s;
}

// ===========================================================================
// logits128: Lg[z][q][kt] = PQ[cg] . PKf[cg]; row0 -= cfx. grid (13,13,na)
// ===========================================================================
__global__ void logits128(const short* __restrict__ PQ, const short* __restrict__ PKf,
                          const float* __restrict__ cfx, int a0, float* __restrict__ Lg) {
  __shared__ __align__(16) short As[128 * BK];
  __shared__ __align__(16) short Bs[128 * BK];
  int q0 = blockIdx.x * 128, k0 = blockIdx.y * 128, z = blockIdx.z;
  int cg = a0 + z;
  int tid = threadIdx.x, lane = tid & 63, w = tid >> 6, wr = w >> 1, wc = w & 1;
  int rbase = tid >> 3;
  int ss = ((tid & 7) ^ (rbase & 7)) << 3;
  const short* Aq = PQ + (size_t)cg * LP * 512;
  const short* Bk = PKf + (size_t)cg * LP * 512;
  f32x4 acc[4][4] = {};
  for (int kq = 0; kq < 512; kq += BK) {
    #pragma unroll
    for (int p = 0; p < 4; ++p) {
      int row = rbase + 32 * p;
      int ar = q0 + row; if (ar > LL2 - 1) ar = LL2 - 1;
      int br = k0 + row; if (br > LL2 - 1) br = LL2 - 1;
      gload16(Aq + (size_t)ar * 512 + kq + ss, As + (32 * p + 8 * w) * BK);
      gload16(Bk + (size_t)br * 512 + kq + ss, Bs + (32 * p + 8 * w) * BK);
    }
    __syncthreads();
    mma128(As, Bs, lane, wr, wc, acc);
    __syncthreads();
  }
  int m = lane & 15, quad = lane >> 4;
  float* lg = Lg + (size_t)z * LP * LP;
  const float* cf = cfx + (size_t)cg * LP;
  #pragma unroll
  for (int i = 0; i < 4; ++i)
    #pragma unroll
    for (int j = 0; j < 4; ++j)
      #pragma unroll
      for (int e = 0; e < 4; ++e) {
        int q = q0 + wr * 64 + i * 16 + quad * 4 + e;
        int kt = k0 + wc * 64 + j * 16 + m;
        if (q >= LP || kt >= LP) continue;
        float val = acc[i][j][e];
        if (q == 0) val -= cf[kt];
        lg[(size_t)q * LP + kt] = val;
      }
}

// softmax row (f32) -> bf16 attn in place
__global__ void softmax_kernel(float* __restrict__ Lg) {
  int q = blockIdx.x, z = blockIdx.y;
  float* p = Lg + ((size_t)z * LP + q) * LP;
  __shared__ float buf[LP];
  __shared__ float red[256];
  int tid = threadIdx.x;
  float mx = -1e30f;
  for (int j = tid; j < LL2; j += 256) { float v = p[j]; buf[j] = v; mx = fmaxf(mx, v); }
  red[tid] = mx; __syncthreads();
  for (int s = 128; s; s >>= 1) { if (tid < s) red[tid] = fmaxf(red[tid], red[tid + s]); __syncthreads(); }
  mx = red[0]; __syncthreads();
  float sum = 0.f;
  for (int j = tid; j < LL2; j += 256) { float e = __expf(buf[j] - mx); buf[j] = e; sum += e; }
  red[tid] = sum; __syncthreads();
  for (int s = 128; s; s >>= 1) { if (tid < s) red[tid] += red[tid + s]; __syncthreads(); }
  float inv = 1.f / red[0];
  short* o = (short*)p;
  for (int j = tid; j < LL2; j += 256) o[j] = f2bs(buf[j] * inv);
  for (int j = LL2 + tid; j < LP; j += 256) o[j] = 0;
}

// ===========================================================================
// av128: Outb[gg][q][n] = attn @ PVt + (q==0?1:2)*PQ. grid (13,4,na)
// ===========================================================================
__global__ void av128(const float* __restrict__ Lg, const short* __restrict__ PVt,
                      const short* __restrict__ PQ, short* __restrict__ Outb,
                      int h0, int CH, int a0) {
  __shared__ __align__(16) short As[128 * BK];
  __shared__ __align__(16) short Bs[128 * BK];
  int q0 = blockIdx.x * 128, n0 = blockIdx.y * 128, z = blockIdx.z;
  int cg = a0 + z;
  int b = cg / CH, gg = b * 8 + h0 + cg % CH;
  int tid = threadIdx.x, lane = tid & 63, w = tid >> 6, wr = w >> 1, wc = w & 1;
  int rbase = tid >> 3;
  int ss = ((tid & 7) ^ (rbase & 7)) << 3;
  const short* Aat = (const short*)(Lg + (size_t)z * LP * LP);  // bf16 rows, stride 2*LP
  const short* Bv = PVt + (size_t)cg * 512 * LP;
  f32x4 acc[4][4] = {};
  for (int kq = 0; kq < LP; kq += BK) {
    #pragma unroll
    for (int p = 0; p < 4; ++p) {
      int row = rbase + 32 * p;
      int ar = q0 + row; if (ar > LP - 1) ar = LP - 1;
      gload16(Aat + (size_t)ar * (2 * LP) + kq + ss, As + (32 * p + 8 * w) * BK);
      gload16(Bv + (size_t)(n0 + row) * LP + kq + ss, Bs + (32 * p + 8 * w) * BK);
    }
    __syncthreads();
    mma128(As, Bs, lane, wr, wc, acc);
    __syncthreads();
  }
  int m = lane & 15, quad = lane >> 4;
  #pragma unroll
  for (int i = 0; i < 4; ++i)
    #pragma unroll
    for (int j = 0; j < 4; ++j)
      #pragma unroll
      for (int e = 0; e < 4; ++e) {
        int q = q0 + wr * 64 + i * 16 + quad * 4 + e;
        if (q >= LL2) continue;
        int n = n0 + wc * 64 + j * 16 + m;
        float res = bs2f(PQ[((size_t)cg * LP + q) * 512 + n]);
        float val = acc[i][j][e] + (q == 0 ? 1.f : 2.f) * res;
        Outb[((size_t)gg * LP + q) * 512 + n] = f2bs(val);
      }
}

// ===========================================================================
// final128: Y = stacked @ Wd^T + bd + PX. grid (25, 4). M=3138 flat (b,q).
// ===========================================================================
__global__ void final128(const short* __restrict__ Outb, const short* __restrict__ WdB,
                         const float* __restrict__ bd, const short* __restrict__ PX,
                         float* __restrict__ Y) {
  __shared__ __align__(16) short As[128 * BK];
  __shared__ __align__(16) short Bs[128 * BK];
  int mf0 = blockIdx.x * 128, n0 = blockIdx.y * 128;
  int tid = threadIdx.x, lane = tid & 63, w = tid >> 6, wr = w >> 1, wc = w & 1;
  int rbase = tid >> 3;
  int ss = ((tid & 7) ^ (rbase & 7)) << 3;
  const int M = Bb * LL2;  // 3138
  int brow[4], qrow[4];
  #pragma unroll
  for (int p = 0; p < 4; ++p) {
    int mf = mf0 + rbase + 32 * p; if (mf > M - 1) mf = M - 1;
    brow[p] = mf / LL2; qrow[p] = mf % LL2;
  }
  f32x4 acc[4][4] = {};
  for (int kq = 0; kq < 4096; kq += BK) {
    int hh = kq >> 9, koff = kq & 511;
    #pragma unroll
    for (int p = 0; p < 4; ++p) {
      int row = rbase + 32 * p;
      gload16(Outb + ((size_t)(brow[p] * 8 + hh) * LP + qrow[p]) * 512 + koff + ss,
              As + (32 * p + 8 * w) * BK);
      gload16(WdB + (size_t)(n0 + row) * 4096 + kq + ss,
              Bs + (32 * p + 8 * w) * BK);
    }
    __syncthreads();
    mma128(As, Bs, lane, wr, wc, acc);
    __syncthreads();
  }
  int m = lane & 15, quad = lane >> 4;
  #pragma unroll
  for (int i = 0; i < 4; ++i)
    #pragma unroll
    for (int j = 0; j < 4; ++j)
      #pragma unroll
      for (int e = 0; e < 4; ++e) {
        int mf = mf0 + wr * 64 + i * 16 + quad * 4 + e;
        if (mf >= M) continue;
        int b2 = mf / LL2, q2 = mf % LL2;
        int dm = n0 + wc * 64 + j * 16 + m;
        float val = acc[i][j][e] + bd[dm] + bs2f(PX[((size_t)b2 * LP + q2) * 512 + dm]);
        Y[(size_t)mf * 512 + dm] = val;
      }
}

// LayerNorm over 512
__global__ void ln_kernel(const float* __restrict__ Y, const float* __restrict__ gamma,
                          const float* __restrict__ beta, float* __restrict__ Outp) {
  int row = blockIdx.x;
  const float* y = Y + (size_t)row * 512;
  __shared__ float red[256];
  int tid = threadIdx.x;
  float v0 = y[tid], v1 = y[tid + 256];
  red[tid] = v0 + v1; __syncthreads();
  for (int s = 128; s; s >>= 1) { if (tid < s) red[tid] += red[tid + s]; __syncthreads(); }
  float mu = red[0] * (1.f / 512.f);
  __syncthreads();
  float d0 = v0 - mu, d1 = v1 - mu;
  red[tid] = d0 * d0 + d1 * d1; __syncthreads();
  for (int s = 128; s; s >>= 1) { if (tid < s) red[tid] += red[tid + s]; __syncthreads(); }
  float rstd = rsqrtf(red[0] * (1.f / 512.f) + 1e-5f);
  float* o = Outp + (size_t)row * 512;
  o[tid]       = d0 * rstd * gamma[tid]       + beta[tid];
  o[tid + 256] = d1 * rstd * gamma[tid + 256] + beta[tid + 256];
}

// ---------------------------------------------------------------------------
extern "C" void kernel_launch(void* const* d_in, const int* in_sizes, int n_in,
                              void* d_out, int out_size, void* d_ws, size_t ws_size,
                              hipStream_t stream) {
  const float* x     = (const float*)d_in[0];
  const float* Wq    = (const float*)d_in[1];
  const float* bq    = (const float*)d_in[2];
  const float* Wk    = (const float*)d_in[3];
  const float* bk    = (const float*)d_in[4];
  const float* Wv    = (const float*)d_in[5];
  const float* bv    = (const float*)d_in[6];
  const float* wpq   = (const float*)d_in[7];
  const float* wpk   = (const float*)d_in[8];
  const float* wpv   = (const float*)d_in[9];
  const float* wpx   = (const float*)d_in[10];
  const float* Wd    = (const float*)d_in[11];
  const float* bd    = (const float*)d_in[12];
  const float* gamma = (const float*)d_in[13];
  const float* beta  = (const float*)d_in[14];
  float* outp = (float*)d_out;

  auto rnd = [](size_t b) { return (b + 255) / 256 * 256; };
  const size_t persist =
      rnd((size_t)LP * 512 * 4) +            // embz
      rnd((size_t)Bb * Ll * 512 * 2) +       // xbf
      4 * rnd((size_t)512 * 2048 * 2) +      // wpxT + wpqT/wpkT/wpvT
      3 * rnd((size_t)8 * 512 * 512 * 2) +   // WqT/WkT/WvT
      rnd((size_t)512 * 4096 * 2) +          // WdB
      rnd((size_t)16 * LP * 512 * 2) +       // Outb
      rnd((size_t)2 * LP * 512 * 2) +        // PX
      rnd((size_t)2 * LL2 * 512 * 4) +       // Y
      rnd((size_t)16 * LP * 4);              // cfx
  auto chpart = [&](int CH) {
    return rnd((size_t)3 * CH * 512 * 2048 * 2) + rnd((size_t)3 * CH * 512 * 4) +
           3 * rnd((size_t)2 * CH * LP * 512 * 2);
  };
  const size_t lgbytes = rnd((size_t)LP * LP * 4);
  int CH = 8;
  while (CH > 1 && persist + chpart(CH) + lgbytes > ws_size) CH >>= 1;
  if (persist + chpart(CH) + lgbytes > ws_size) return;
  int NA = (int)((ws_size - persist - chpart(CH)) / lgbytes);
  if (NA > 2 * CH) NA = 2 * CH;
  int nc = 8 / CH;

  char* w = (char*)d_ws;
  auto alloc = [&](size_t bytes) { char* p = w; w += (bytes + 255) / 256 * 256; return p; };
  float* embz = (float*)alloc((size_t)LP * 512 * 4);
  short* xbf  = (short*)alloc((size_t)Bb * Ll * 512 * 2);
  short* wpxT = (short*)alloc((size_t)512 * 2048 * 2);
  short* wpqT = (short*)alloc((size_t)512 * 2048 * 2);
  short* wpkT = (short*)alloc((size_t)512 * 2048 * 2);
  short* wpvT = (short*)alloc((size_t)512 * 2048 * 2);
  short* WqT  = (short*)alloc((size_t)8 * 512 * 512 * 2);
  short* WkT  = (short*)alloc((size_t)8 * 512 * 512 * 2);
  short* WvT  = (short*)alloc((size_t)8 * 512 * 512 * 2);
  short* WdB  = (short*)alloc((size_t)512 * 4096 * 2);
  short* Outb = (short*)alloc((size_t)16 * LP * 512 * 2);
  short* PX   = (short*)alloc((size_t)2 * LP * 512 * 2);
  float* Y    = (float*)alloc((size_t)2 * LL2 * 512 * 4);
  float* cfx  = (float*)alloc((size_t)16 * LP * 4);
  short* Weff = (short*)alloc((size_t)3 * CH * 512 * 2048 * 2);
  float* beff = (float*)alloc((size_t)3 * CH * 512 * 4);
  short* PQ   = (short*)alloc((size_t)2 * CH * LP * 512 * 2);
  short* PKf  = (short*)alloc((size_t)2 * CH * LP * 512 * 2);
  short* PVt  = (short*)alloc((size_t)2 * CH * LP * 512 * 2);
  float* Lg   = (float*)alloc((size_t)NA * LP * LP * 4);

  dim3 blk(256);
  emb_kernel<<<dim3((LP * 512 + 255) / 256), blk, 0, stream>>>(embz);
  cvt_kernel<<<dim3((Bb * Ll * 512 / 4 + 255) / 256), blk, 0, stream>>>(x, xbf, Bb * Ll * 512 / 4);
  wpxt_kernel<<<dim3(4096), blk, 0, stream>>>(wpx, wpxT);
  wpxt_kernel<<<dim3(4096), blk, 0, stream>>>(wpq, wpqT);
  wpxt_kernel<<<dim3(4096), blk, 0, stream>>>(wpk, wpkT);
  wpxt_kernel<<<dim3(4096), blk, 0, stream>>>(wpv, wpvT);
  tr_w_kernel<<<dim3(8, 8, 8), blk, 0, stream>>>(Wq, WqT);
  tr_w_kernel<<<dim3(8, 8, 8), blk, 0, stream>>>(Wk, WkT);
  tr_w_kernel<<<dim3(8, 8, 8), blk, 0, stream>>>(Wv, WvT);
  cvt_kernel<<<dim3((512 * 4096 / 4 + 255) / 256), blk, 0, stream>>>(Wd, WdB, 512 * 4096 / 4);
  px_pool<<<dim3(50, 8), blk, 0, stream>>>(xbf, wpxT, PX);
  pxcls_kernel<<<dim3(2), dim3(512), 0, stream>>>(x, PX);

  for (int c = 0; c < nc; ++c) {
    int h0 = c * CH;
    weff128<<<dim3(4, 4, 12 * CH), blk, 0, stream>>>(wpqT, wpkT, wpvT, WqT, WkT, WvT,
                                                     h0, CH, Weff);
    beff_fused<<<dim3(3, CH), blk, 0, stream>>>(bq, bk, bv, wpq, wpk, wpv, h0, CH, beff);
    pool128x2<<<dim3(13 * 12 * CH), blk, 0, stream>>>(xbf, Weff, beff, embz,
                                                      PQ, PKf, PVt, CH);
    cls_fast<<<dim3(128, 3, 2 * CH), blk, 0, stream>>>(xbf, Wq, bq, Wk, bk, Wv, bv,
                                                       h0, CH, PQ, PKf, PVt);
    for (int a0 = 0; a0 < 2 * CH; a0 += NA) {
      int na = (2 * CH - a0) < NA ? (2 * CH - a0) : NA;
      cfix_kernel<<<dim3(400, na), blk, 0, stream>>>(PQ, embz, a0, cfx);
      logits128<<<dim3(13, 13, na), blk, 0, stream>>>(PQ, PKf, cfx, a0, Lg);
      softmax_kernel<<<dim3(LL2, na), blk, 0, stream>>>(Lg);
      av128<<<dim3(13, 4, na), blk, 0, stream>>>(Lg, PVt, PQ, Outb, h0, CH, a0);
    }
  }

  final128<<<dim3(25, 4), blk, 0, stream>>>(Outb, WdB, bd, PX, Y);
  ln_kernel<<<dim3(Bb * LL2), blk, 0, stream>>>(Y, gamma, beta, outp);
}

// Round 8
// 1077.932 us; speedup vs baseline: 2.4901x; 1.1692x over previous
//
#include <hip/hip_runtime.h>
#include <hip/hip_bf16.h>
#include <cstdint>
#include <cstddef>

typedef __hip_bfloat16 bf16;
typedef __attribute__((ext_vector_type(8))) short short8;   // 8 bf16 in 4 VGPRs
typedef __attribute__((ext_vector_type(4))) short short4v;
typedef __attribute__((ext_vector_type(4))) float f32x4;
#define DEVI __device__ __forceinline__

constexpr int Bb = 2, Ll = 6273, Pp = 1568, LL2 = 1569, LP = 1600;
constexpr float QK_SCALE = 0.04419417382415922f;  // 512^-0.5

DEVI short f2bs(float f) {
  __hip_bfloat16 h = __float2bfloat16(f);
  return __builtin_bit_cast(short, h);
}
DEVI float bs2f(short s) {
  __hip_bfloat16 h = __builtin_bit_cast(__hip_bfloat16, s);
  return __bfloat162float(h);
}

// async global->LDS, 16B per lane. LDS dest = wave-uniform base + lane*16.
DEVI void gload16(const short* g, short* l) {
  __builtin_amdgcn_global_load_lds(
      (const __attribute__((address_space(1))) void*)g,
      (__attribute__((address_space(3))) void*)l,
      16, 0, 0);
}

// ===========================================================================
// 128x128 MFMA tile core, BK=64, 256 threads = 4 waves in 2x2 (each 64x64 via
// 4x4 frags of mfma_f32_16x16x32_bf16). PROVEN schedule (R1, 1056us):
// single-buffer stage -> __syncthreads -> mma -> __syncthreads.
// Register ledger (R5-R7 lessons):
//  - no __launch_bounds__ => 128-reg/wave cap => wide acc spills (R5/R6:
//    WRITE 2.9GB, MfmaUtil 6%).
//  - __launch_bounds__(256) uncapped => 280 regs/wave => 1 block/CU =>
//    latency-bound (R7: Occ 10.6%, 489us).
//  - fix: __launch_bounds__(256,2) caps at 256 regs/wave (2 waves/EU) AND
//    mma128_dual shares b[4] across both A-tiles to cut demand to ~200.
// 16B-slot XOR swizzle (slot ^= row&7) -> conflict-free b128 reads.
// Staging: global_load_lds LINEAR dest + inverse-swizzled per-lane global
// SOURCE (rule 21). C/D layout per m89: col=lane&15, row=quad*4+e.
// ===========================================================================
constexpr int BK = 64;

DEVI int sw_idx(int row, int slot) {            // slot = 16B unit (8 shorts)
  return row * BK + (((slot) ^ (row & 7)) << 3);
}

DEVI void mma128(const short* As, const short* Bs, int lane, int wr, int wc,
                 f32x4 (&acc)[4][4]) {
  int m = lane & 15, quad = lane >> 4;
  #pragma unroll
  for (int kh = 0; kh < 2; ++kh) {
    int slot = kh * 4 + quad;
    short8 a[4], b[4];
    #pragma unroll
    for (int i = 0; i < 4; ++i) {
      int row = wr * 64 + i * 16 + m;
      a[i] = *(const short8*)(As + sw_idx(row, slot));
    }
    #pragma unroll
    for (int j = 0; j < 4; ++j) {
      int row = wc * 64 + j * 16 + m;
      b[j] = *(const short8*)(Bs + sw_idx(row, slot));
    }
    #pragma unroll
    for (int i = 0; i < 4; ++i)
      #pragma unroll
      for (int j = 0; j < 4; ++j)
        acc[i][j] = __builtin_amdgcn_mfma_f32_16x16x32_bf16(a[i], b[j], acc[i][j], 0, 0, 0);
  }
}

// Dual-A core: loads shared b[4] ONCE for two A-tiles (saves 16 VGPRs of
// pressure and half the B-side ds_read traffic vs two mma128 calls).
DEVI void mma128_dual(const short* As0, const short* As1, const short* Bs,
                      int lane, int wr, int wc,
                      f32x4 (&acc0)[4][4], f32x4 (&acc1)[4][4]) {
  int m = lane & 15, quad = lane >> 4;
  #pragma unroll
  for (int kh = 0; kh < 2; ++kh) {
    int slot = kh * 4 + quad;
    short8 b[4];
    #pragma unroll
    for (int j = 0; j < 4; ++j)
      b[j] = *(const short8*)(Bs + sw_idx(wc * 64 + j * 16 + m, slot));
    #pragma unroll
    for (int i = 0; i < 4; ++i) {
      int row = wr * 64 + i * 16 + m;
      short8 a0 = *(const short8*)(As0 + sw_idx(row, slot));
      short8 a1 = *(const short8*)(As1 + sw_idx(row, slot));
      #pragma unroll
      for (int j = 0; j < 4; ++j) {
        acc0[i][j] = __builtin_amdgcn_mfma_f32_16x16x32_bf16(a0, b[j], acc0[i][j], 0, 0, 0);
        acc1[i][j] = __builtin_amdgcn_mfma_f32_16x16x32_bf16(a1, b[j], acc1[i][j], 0, 0, 0);
      }
    }
  }
}

// Old 64x64 core (kept for the small px_pool only)
constexpr int LDT = 40;
DEVI void mma_step(const short* As, const short* Bs, int lane, int wr, int wc,
                   f32x4& c00, f32x4& c01, f32x4& c10, f32x4& c11) {
  int m = lane & 15, quad = lane >> 4;
  const short* a = As + (wr * 32 + m) * LDT + quad * 8;
  const short* b = Bs + (wc * 32 + m) * LDT + quad * 8;
  short8 a0 = *(const short8*)a;
  short8 a1 = *(const short8*)(a + 16 * LDT);
  short8 b0 = *(const short8*)b;
  short8 b1 = *(const short8*)(b + 16 * LDT);
  c00 = __builtin_amdgcn_mfma_f32_16x16x32_bf16(a0, b0, c00, 0, 0, 0);
  c01 = __builtin_amdgcn_mfma_f32_16x16x32_bf16(a0, b1, c01, 0, 0, 0);
  c10 = __builtin_amdgcn_mfma_f32_16x16x32_bf16(a1, b0, c10, 0, 0, 0);
  c11 = __builtin_amdgcn_mfma_f32_16x16x32_bf16(a1, b1, c11, 0, 0, 0);
}

// ---------------------------------------------------------------------------
__global__ void emb_kernel(float* __restrict__ embz) {
  int idx = blockIdx.x * 256 + threadIdx.x;
  if (idx >= LP * 512) return;
  int p = idx >> 9, d = idx & 511;
  float v = 0.f;
  if (p > 0 && p < LL2) {
    int pb = p - 1;
    int t = pb / 196, r = pb % 196;
    int h = r / 14, ww = r % 14;
    int pos, j, half;
    if (d < 170)      { pos = t;  j = d;       half = 85; }
    else if (d < 340) { pos = h;  j = d - 170; half = 85; }
    else              { pos = ww; j = d - 340; half = 86; }
    int jj = (j < half) ? j : (j - half);
    float omega = powf(10000.f, -(float)jj / (float)half);
    float ang = (float)pos * omega;
    v = (j < half) ? sinf(ang) : cosf(ang);
  }
  embz[idx] = v;
}

// f32 -> bf16 bulk convert, 4 elements/thread
__global__ void cvt_kernel(const float* __restrict__ src, short* __restrict__ dst, int n4) {
  int idx = blockIdx.x * 256 + threadIdx.x;
  if (idx >= n4) return;
  float4 v = *(const float4*)(src + (size_t)idx * 4);
  short4v o = { f2bs(v.x), f2bs(v.y), f2bs(v.z), f2bs(v.w) };
  *(short4v*)(dst + (size_t)idx * 4) = o;
}

// wpT[n][tap*512+k] = bf16(wp[n*2048 + k*4 + tap])  (works for wpx/wpq/wpk/wpv)
__global__ void wpxt_kernel(const float* __restrict__ wp, short* __restrict__ wpT) {
  int idx = blockIdx.x * 256 + threadIdx.x;
  if (idx >= 512 * 2048) return;
  int n = idx >> 11, rem = idx & 2047, tap = rem >> 9, k = rem & 511;
  wpT[idx] = f2bs(wp[n * 2048 + k * 4 + tap]);
}

// WT[h][k][i] = bf16(W[(h*512+i)*512 + k])
__global__ void tr_w_kernel(const float* __restrict__ W, short* __restrict__ WT) {
  __shared__ float Ws[64][65];
  int i0 = blockIdx.x * 64, k0 = blockIdx.y * 64, h = blockIdx.z;
  int tid = threadIdx.x;
  int r = tid >> 2, c0 = (tid & 3) * 16;
  const float* src = W + ((size_t)(h * 512 + i0 + r)) * 512 + k0 + c0;
  #pragma unroll
  for (int j = 0; j < 16; ++j) Ws[r][c0 + j] = src[j];
  __syncthreads();
  short* dst = WT + ((size_t)(h * 512 + k0 + r)) * 512 + i0 + c0;
  #pragma unroll
  for (int j = 0; j < 16; ++j) dst[j] = f2bs(Ws[c0 + j][r]);
}

// ===========================================================================
// weff128: Weff[(mat*CH+ch)*512+n][tap*512+k] = sum_i wpT[n][tap*512+i]*WT[h][k][i]
// grid (4, 4, 12*CH) — R1 single-buffer schedule
// ===========================================================================
__global__ void weff128(const short* __restrict__ wpqT, const short* __restrict__ wpkT,
                        const short* __restrict__ wpvT,
                        const short* __restrict__ WqT, const short* __restrict__ WkT,
                        const short* __restrict__ WvT,
                        int h0, int CH, short* __restrict__ Weff) {
  __shared__ __align__(16) short As[128 * BK];
  __shared__ __align__(16) short Bs[128 * BK];
  int n0 = blockIdx.x * 128, k0 = blockIdx.y * 128;
  int z = blockIdx.z;
  int mat = z / (4 * CH), rem = z % (4 * CH);
  int ch = rem >> 2, tap = rem & 3;
  const short* wpT = mat == 0 ? wpqT : (mat == 1 ? wpkT : wpvT);
  const short* WT  = mat == 0 ? WqT  : (mat == 1 ? WkT  : WvT);
  int h = h0 + ch;
  int tid = threadIdx.x, lane = tid & 63, w = tid >> 6, wr = w >> 1, wc = w & 1;
  int rbase = tid >> 3;
  int ss = ((tid & 7) ^ (rbase & 7)) << 3;   // pre-swizzled source slot (shorts)
  f32x4 acc[4][4] = {};
  for (int kq = 0; kq < 512; kq += BK) {
    #pragma unroll
    for (int p = 0; p < 4; ++p) {
      int row = rbase + 32 * p;
      gload16(wpT + (size_t)(n0 + row) * 2048 + tap * 512 + kq + ss,
              As + (32 * p + 8 * w) * BK);
      gload16(WT + ((size_t)(h * 512 + k0 + row)) * 512 + kq + ss,
              Bs + (32 * p + 8 * w) * BK);
    }
    __syncthreads();
    mma128(As, Bs, lane, wr, wc, acc);
    __syncthreads();
  }
  int m = lane & 15, quad = lane >> 4;
  size_t base = ((size_t)(mat * CH + ch) * 512) * 2048 + tap * 512;
  #pragma unroll
  for (int i = 0; i < 4; ++i)
    #pragma unroll
    for (int j = 0; j < 4; ++j)
      #pragma unroll
      for (int e = 0; e < 4; ++e) {
        int n = n0 + wr * 64 + i * 16 + quad * 4 + e;
        int k = k0 + wc * 64 + j * 16 + m;
        Weff[base + (size_t)n * 2048 + k] = f2bs(acc[i][j][e]);
      }
}

// beff_all[(mat*CH+ch)][n]
__global__ void beff_fused(const float* __restrict__ bq, const float* __restrict__ bk,
                           const float* __restrict__ bv,
                           const float* __restrict__ wpq, const float* __restrict__ wpk,
                           const float* __restrict__ wpv,
                           int h0, int CH, float* __restrict__ beff) {
  int mat = blockIdx.x, ch = blockIdx.y, tid = threadIdx.x;
  const float* bias = mat == 0 ? bq : (mat == 1 ? bk : bv);
  const float* wp = mat == 0 ? wpq : (mat == 1 ? wpk : wpv);
  for (int n = tid; n < 512; n += 256) {
    float s = 0.f;
    for (int i = 0; i < 512; ++i) {
      float bi = bias[(h0 + ch) * 512 + i];
      const float* w4 = wp + (size_t)n * 2048 + i * 4;
      s += bi * (w4[0] + w4[1] + w4[2] + w4[3]);
    }
    beff[(mat * CH + ch) * 512 + n] = s;
  }
}

// ===========================================================================
// pool128x2: one B-tile (128 Weff cols) shared by TWO A-tiles per block.
// __launch_bounds__(256, 2) => cap 256 regs/wave => 2 blocks/CU (R7 fix);
// mma128_dual shares b[4] so demand ~200 regs => no spill expected.
// 256 threads, LDS 48KB. grid 13*12*CH, bijective XCD swizzle (m204).
// ===========================================================================
__global__ void __launch_bounds__(256, 2)
pool128x2(const short* __restrict__ xbf, const short* __restrict__ Weff,
          const float* __restrict__ beff, const float* __restrict__ embz,
          short* __restrict__ PQ, short* __restrict__ PKf,
          short* __restrict__ PVt, int CH) {
  int NT = 12 * CH;
  int nwg = 13 * NT;
  int bid = blockIdx.x;
  int q8 = nwg >> 3, r8 = nwg & 7;
  int xcd = bid & 7, lin = bid >> 3;
  int wgid = (xcd < r8 ? xcd * (q8 + 1) : r8 * (q8 + 1) + (xcd - r8) * q8) + lin;
  int nt = wgid % NT, pr = wgid / NT;        // pr in 0..12
  int mb0 = pr * 2, mb1 = pr * 2 + 1;        // two m-tiles share one B-tile
  int mt0 = mb0 % 13, b0 = mb0 / 13;
  int mt1 = mb1 % 13, b1 = mb1 / 13;
  int mat = nt / (4 * CH), ch = (nt >> 2) % CH;
  int n0t = (nt & 3) * 128;

  __shared__ __align__(16) short As0[128 * BK];
  __shared__ __align__(16) short As1[128 * BK];
  __shared__ __align__(16) short Bs[128 * BK];
  int tid = threadIdx.x, lane = tid & 63, w = tid >> 6, wr = w >> 1, wc = w & 1;
  int rbase = tid >> 3;
  int ss = ((tid & 7) ^ (rbase & 7)) << 3;
  // prologue: pooled-position source bases (in shorts) for the staged rows
  int srcA0[4], srcA1[4];
  #pragma unroll
  for (int p = 0; p < 4; ++p) {
    int row = rbase + 32 * p;
    int pb0 = mt0 * 128 + row; if (pb0 > Pp - 1) pb0 = Pp - 1;
    int t3 = pb0 / 196, rm = pb0 % 196, h2 = rm / 14, w2 = rm % 14;
    srcA0[p] = b0 * (Ll * 512) + (1 + t3 * 784 + h2 * 56 + w2 * 2) * 512;
    int pb1 = mt1 * 128 + row; if (pb1 > Pp - 1) pb1 = Pp - 1;
    int t3b = pb1 / 196, rmb = pb1 % 196, h2b = rmb / 14, w2b = rmb % 14;
    srcA1[p] = b1 * (Ll * 512) + (1 + t3b * 784 + h2b * 56 + w2b * 2) * 512;
  }

  f32x4 acc0[4][4] = {};
  f32x4 acc1[4][4] = {};
  for (int kq = 0; kq < 2048; kq += BK) {
    int tap = kq >> 9, koff = kq & 511;
    int tr = ((tap & 1) + (tap >> 1) * 28) * 512;   // taprow {0,1,28,29} in shorts
    #pragma unroll
    for (int p = 0; p < 4; ++p) {
      int row = rbase + 32 * p;
      gload16(xbf + (size_t)(srcA0[p] + tr + koff + ss), As0 + (32 * p + 8 * w) * BK);
      gload16(xbf + (size_t)(srcA1[p] + tr + koff + ss), As1 + (32 * p + 8 * w) * BK);
      gload16(Weff + ((size_t)nt * 128 + row) * 2048 + kq + ss,
              Bs + (32 * p + 8 * w) * BK);
    }
    __syncthreads();
    mma128_dual(As0, As1, Bs, lane, wr, wc, acc0, acc1);
    __syncthreads();
  }
  int m = lane & 15, quad = lane >> 4;
  int bb = (mat * CH + ch) * 512;
  // epilogue for acc0 (hand-expanded)
  {
    int cg = b0 * CH + ch;
    #pragma unroll
    for (int i = 0; i < 4; ++i)
      #pragma unroll
      for (int j = 0; j < 4; ++j)
        #pragma unroll
        for (int e = 0; e < 4; ++e) {
          int row = wr * 64 + i * 16 + quad * 4 + e;
          int pb = mt0 * 128 + row;
          if (pb >= Pp) continue;
          int tok = pb + 1;
          int n = n0t + wc * 64 + j * 16 + m;
          float val = acc0[i][j][e] + beff[bb + n];
          if (mat == 0)      PQ[((size_t)cg * LP + tok) * 512 + n] = f2bs(val);
          else if (mat == 1) PKf[((size_t)cg * LP + tok) * 512 + n] =
                                 f2bs(val * QK_SCALE + embz[(size_t)tok * 512 + n]);
          else               PVt[((size_t)cg * 512 + n) * LP + tok] = f2bs(val);
        }
  }
  // epilogue for acc1
  {
    int cg = b1 * CH + ch;
    #pragma unroll
    for (int i = 0; i < 4; ++i)
      #pragma unroll
      for (int j = 0; j < 4; ++j)
        #pragma unroll
        for (int e = 0; e < 4; ++e) {
          int row = wr * 64 + i * 16 + quad * 4 + e;
          int pb = mt1 * 128 + row;
          if (pb >= Pp) continue;
          int tok = pb + 1;
          int n = n0t + wc * 64 + j * 16 + m;
          float val = acc1[i][j][e] + beff[bb + n];
          if (mat == 0)      PQ[((size_t)cg * LP + tok) * 512 + n] = f2bs(val);
          else if (mat == 1) PKf[((size_t)cg * LP + tok) * 512 + n] =
                                 f2bs(val * QK_SCALE + embz[(size_t)tok * 512 + n]);
          else               PVt[((size_t)cg * 512 + n) * LP + tok] = f2bs(val);
        }
  }
}

// PX pooled GEMM (64-tile; small)
__global__ void px_pool(const short* __restrict__ xbf, const short* __restrict__ wpxT,
                        short* __restrict__ PX) {
  __shared__ short As[64 * LDT];
  __shared__ short Bs[64 * LDT];
  int mt = blockIdx.x % 25, b = blockIdx.x / 25;
  int n0 = blockIdx.y * 64;
  int tid = threadIdx.x, lane = tid & 63, w = tid >> 6, wr = w >> 1, wc = w & 1;
  int sr = tid >> 2, sc = (tid & 3) * 8;
  int mloc = mt * 64 + sr;
  int pb = mloc < Pp ? mloc : (Pp - 1);
  int t3 = pb / 196, rm = pb % 196, h2 = rm / 14, w2 = rm % 14;
  int l0 = 1 + t3 * 784 + h2 * 56 + w2 * 2;
  const short* xb = xbf + (size_t)b * Ll * 512;
  f32x4 acc[2][2] = {};
  for (int kq = 0; kq < 2048; kq += 32) {
    int tap = kq >> 9;
    int lrow = l0 + (tap >> 1) * 28 + (tap & 1);
    *(short8*)(As + sr * LDT + sc) =
        *(const short8*)(xb + (size_t)lrow * 512 + (kq & 511) + sc);
    *(short8*)(Bs + sr * LDT + sc) =
        *(const short8*)(wpxT + (size_t)(n0 + sr) * 2048 + kq + sc);
    __syncthreads();
    mma_step(As, Bs, lane, wr, wc, acc[0][0], acc[0][1], acc[1][0], acc[1][1]);
    __syncthreads();
  }
  int m = lane & 15, quad = lane >> 4;
  #pragma unroll
  for (int ri = 0; ri < 2; ++ri)
    #pragma unroll
    for (int ci = 0; ci < 2; ++ci)
      #pragma unroll
      for (int e = 0; e < 4; ++e) {
        int mrow = mt * 64 + wr * 32 + ri * 16 + quad * 4 + e;
        int tok = mrow + 1; if (tok > LP - 1) tok = LP - 1;
        int n = n0 + wc * 32 + ci * 16 + m;
        PX[((size_t)b * LP + tok) * 512 + n] = f2bs(acc[ri][ci][e]);
      }
}

// cls row (token 0): one wave per output dot product. grid(128, 3, 2CH)
__global__ void cls_fast(const short* __restrict__ xbf,
                         const float* __restrict__ Wq, const float* __restrict__ bq,
                         const float* __restrict__ Wk, const float* __restrict__ bk,
                         const float* __restrict__ Wv, const float* __restrict__ bv,
                         int h0, int CH,
                         short* __restrict__ PQ, short* __restrict__ PKf,
                         short* __restrict__ PVt) {
  int cg = blockIdx.z, mat = blockIdx.y;
  int wv = threadIdx.x >> 6, lane = threadIdx.x & 63;
  int n = blockIdx.x * 4 + wv;
  int b = cg / CH, h = h0 + cg % CH;
  const float* W = mat == 0 ? Wq : (mat == 1 ? Wk : Wv);
  const float* bias = mat == 0 ? bq : (mat == 1 ? bk : bv);
  const short* xr = xbf + (size_t)b * Ll * 512;
  const float* wr = W + ((size_t)(h * 512 + n)) * 512;
  float s = 0.f;
  #pragma unroll
  for (int j = 0; j < 8; ++j) {
    int k = lane * 8 + j;
    s += bs2f(xr[k]) * wr[k];
  }
  #pragma unroll
  for (int off = 32; off; off >>= 1) s += __shfl_down(s, off, 64);
  if (lane == 0) {
    s += bias[h * 512 + n];
    if (mat == 0)      PQ[((size_t)cg * LP) * 512 + n] = f2bs(s);
    else if (mat == 1) PKf[((size_t)cg * LP) * 512 + n] = f2bs(s * QK_SCALE);
    else               PVt[((size_t)cg * 512 + n) * LP] = f2bs(s);
  }
}

// PX cls row
__global__ void pxcls_kernel(const float* __restrict__ x, short* __restrict__ PX) {
  int b = blockIdx.x, n = threadIdx.x;
  PX[(size_t)b * LP * 512 + n] = f2bs(x[(size_t)b * Ll * 512 + n]);
}

// cfx[cg][kt] = dot(PQ[cg,0,:], embz[kt,:])
__global__ void cfix_kernel(const short* __restrict__ PQ, const float* __restrict__ embz,
                            int a0, float* __restrict__ cfx) {
  int cg = a0 + blockIdx.y;
  int wv = threadIdx.x >> 6, lane = threadIdx.x & 63;
  int kt = blockIdx.x * 4 + wv;
  if (kt >= LP) return;
  int ktc = kt < LL2 ? kt : (LL2 - 1);
  const short* q0 = PQ + (size_t)cg * LP * 512;
  const float* e = embz + (size_t)ktc * 512;
  float s = 0.f;
  #pragma unroll
  for (int j = 0; j < 8; ++j) {
    int d = lane * 8 + j;
    s += bs2f(q0[d]) * e[d];
  }
  #pragma unroll
  for (int off = 32; off; off >>= 1) s += __shfl_down(s, off, 64);
  if (lane == 0) cfx[(size_t)cg * LP + kt] = s;
}

// ===========================================================================
// logits128: Lg[z][q][kt] = PQ[cg] . PKf[cg]; row0 -= cfx. grid (13,13,na)
// ===========================================================================
__global__ void logits128(const short* __restrict__ PQ, const short* __restrict__ PKf,
                          const float* __restrict__ cfx, int a0, float* __restrict__ Lg) {
  __shared__ __align__(16) short As[128 * BK];
  __shared__ __align__(16) short Bs[128 * BK];
  int q0 = blockIdx.x * 128, k0 = blockIdx.y * 128, z = blockIdx.z;
  int cg = a0 + z;
  int tid = threadIdx.x, lane = tid & 63, w = tid >> 6, wr = w >> 1, wc = w & 1;
  int rbase = tid >> 3;
  int ss = ((tid & 7) ^ (rbase & 7)) << 3;
  const short* Aq = PQ + (size_t)cg * LP * 512;
  const short* Bk = PKf + (size_t)cg * LP * 512;
  f32x4 acc[4][4] = {};
  for (int kq = 0; kq < 512; kq += BK) {
    #pragma unroll
    for (int p = 0; p < 4; ++p) {
      int row = rbase + 32 * p;
      int ar = q0 + row; if (ar > LL2 - 1) ar = LL2 - 1;
      int br = k0 + row; if (br > LL2 - 1) br = LL2 - 1;
      gload16(Aq + (size_t)ar * 512 + kq + ss, As + (32 * p + 8 * w) * BK);
      gload16(Bk + (size_t)br * 512 + kq + ss, Bs + (32 * p + 8 * w) * BK);
    }
    __syncthreads();
    mma128(As, Bs, lane, wr, wc, acc);
    __syncthreads();
  }
  int m = lane & 15, quad = lane >> 4;
  float* lg = Lg + (size_t)z * LP * LP;
  const float* cf = cfx + (size_t)cg * LP;
  #pragma unroll
  for (int i = 0; i < 4; ++i)
    #pragma unroll
    for (int j = 0; j < 4; ++j)
      #pragma unroll
      for (int e = 0; e < 4; ++e) {
        int q = q0 + wr * 64 + i * 16 + quad * 4 + e;
        int kt = k0 + wc * 64 + j * 16 + m;
        if (q >= LP || kt >= LP) continue;
        float val = acc[i][j][e];
        if (q == 0) val -= cf[kt];
        lg[(size_t)q * LP + kt] = val;
      }
}

// softmax row (f32) -> bf16 attn in place
__global__ void softmax_kernel(float* __restrict__ Lg) {
  int q = blockIdx.x, z = blockIdx.y;
  float* p = Lg + ((size_t)z * LP + q) * LP;
  __shared__ float buf[LP];
  __shared__ float red[256];
  int tid = threadIdx.x;
  float mx = -1e30f;
  for (int j = tid; j < LL2; j += 256) { float v = p[j]; buf[j] = v; mx = fmaxf(mx, v); }
  red[tid] = mx; __syncthreads();
  for (int s = 128; s; s >>= 1) { if (tid < s) red[tid] = fmaxf(red[tid], red[tid + s]); __syncthreads(); }
  mx = red[0]; __syncthreads();
  float sum = 0.f;
  for (int j = tid; j < LL2; j += 256) { float e = __expf(buf[j] - mx); buf[j] = e; sum += e; }
  red[tid] = sum; __syncthreads();
  for (int s = 128; s; s >>= 1) { if (tid < s) red[tid] += red[tid + s]; __syncthreads(); }
  float inv = 1.f / red[0];
  short* o = (short*)p;
  for (int j = tid; j < LL2; j += 256) o[j] = f2bs(buf[j] * inv);
  for (int j = LL2 + tid; j < LP; j += 256) o[j] = 0;
}

// ===========================================================================
// av128: Outb[gg][q][n] = attn @ PVt + (q==0?1:2)*PQ. grid (13,4,na)
// ===========================================================================
__global__ void av128(const float* __restrict__ Lg, const short* __restrict__ PVt,
                      const short* __restrict__ PQ, short* __restrict__ Outb,
                      int h0, int CH, int a0) {
  __shared__ __align__(16) short As[128 * BK];
  __shared__ __align__(16) short Bs[128 * BK];
  int q0 = blockIdx.x * 128, n0 = blockIdx.y * 128, z = blockIdx.z;
  int cg = a0 + z;
  int b = cg / CH, gg = b * 8 + h0 + cg % CH;
  int tid = threadIdx.x, lane = tid & 63, w = tid >> 6, wr = w >> 1, wc = w & 1;
  int rbase = tid >> 3;
  int ss = ((tid & 7) ^ (rbase & 7)) << 3;
  const short* Aat = (const short*)(Lg + (size_t)z * LP * LP);  // bf16 rows, stride 2*LP
  const short* Bv = PVt + (size_t)cg * 512 * LP;
  f32x4 acc[4][4] = {};
  for (int kq = 0; kq < LP; kq += BK) {
    #pragma unroll
    for (int p = 0; p < 4; ++p) {
      int row = rbase + 32 * p;
      int ar = q0 + row; if (ar > LP - 1) ar = LP - 1;
      gload16(Aat + (size_t)ar * (2 * LP) + kq + ss, As + (32 * p + 8 * w) * BK);
      gload16(Bv + (size_t)(n0 + row) * LP + kq + ss, Bs + (32 * p + 8 * w) * BK);
    }
    __syncthreads();
    mma128(As, Bs, lane, wr, wc, acc);
    __syncthreads();
  }
  int m = lane & 15, quad = lane >> 4;
  #pragma unroll
  for (int i = 0; i < 4; ++i)
    #pragma unroll
    for (int j = 0; j < 4; ++j)
      #pragma unroll
      for (int e = 0; e < 4; ++e) {
        int q = q0 + wr * 64 + i * 16 + quad * 4 + e;
        if (q >= LL2) continue;
        int n = n0 + wc * 64 + j * 16 + m;
        float res = bs2f(PQ[((size_t)cg * LP + q) * 512 + n]);
        float val = acc[i][j][e] + (q == 0 ? 1.f : 2.f) * res;
        Outb[((size_t)gg * LP + q) * 512 + n] = f2bs(val);
      }
}

// ===========================================================================
// final128: Y = stacked @ Wd^T + bd + PX. grid (25, 4). M=3138 flat (b,q).
// ===========================================================================
__global__ void final128(const short* __restrict__ Outb, const short* __restrict__ WdB,
                         const float* __restrict__ bd, const short* __restrict__ PX,
                         float* __restrict__ Y) {
  __shared__ __align__(16) short As[128 * BK];
  __shared__ __align__(16) short Bs[128 * BK];
  int mf0 = blockIdx.x * 128, n0 = blockIdx.y * 128;
  int tid = threadIdx.x, lane = tid & 63, w = tid >> 6, wr = w >> 1, wc = w & 1;
  int rbase = tid >> 3;
  int ss = ((tid & 7) ^ (rbase & 7)) << 3;
  const int M = Bb * LL2;  // 3138
  int brow[4], qrow[4];
  #pragma unroll
  for (int p = 0; p < 4; ++p) {
    int mf = mf0 + rbase + 32 * p; if (mf > M - 1) mf = M - 1;
    brow[p] = mf / LL2; qrow[p] = mf % LL2;
  }
  f32x4 acc[4][4] = {};
  for (int kq = 0; kq < 4096; kq += BK) {
    int hh = kq >> 9, koff = kq & 511;
    #pragma unroll
    for (int p = 0; p < 4; ++p) {
      int row = rbase + 32 * p;
      gload16(Outb + ((size_t)(brow[p] * 8 + hh) * LP + qrow[p]) * 512 + koff + ss,
              As + (32 * p + 8 * w) * BK);
      gload16(WdB + (size_t)(n0 + row) * 4096 + kq + ss,
              Bs + (32 * p + 8 * w) * BK);
    }
    __syncthreads();
    mma128(As, Bs, lane, wr, wc, acc);
    __syncthreads();
  }
  int m = lane & 15, quad = lane >> 4;
  #pragma unroll
  for (int i = 0; i < 4; ++i)
    #pragma unroll
    for (int j = 0; j < 4; ++j)
      #pragma unroll
      for (int e = 0; e < 4; ++e) {
        int mf = mf0 + wr * 64 + i * 16 + quad * 4 + e;
        if (mf >= M) continue;
        int b2 = mf / LL2, q2 = mf % LL2;
        int dm = n0 + wc * 64 + j * 16 + m;
        float val = acc[i][j][e] + bd[dm] + bs2f(PX[((size_t)b2 * LP + q2) * 512 + dm]);
        Y[(size_t)mf * 512 + dm] = val;
      }
}

// LayerNorm over 512
__global__ void ln_kernel(const float* __restrict__ Y, const float* __restrict__ gamma,
                          const float* __restrict__ beta, float* __restrict__ Outp) {
  int row = blockIdx.x;
  const float* y = Y + (size_t)row * 512;
  __shared__ float red[256];
  int tid = threadIdx.x;
  float v0 = y[tid], v1 = y[tid + 256];
  red[tid] = v0 + v1; __syncthreads();
  for (int s = 128; s; s >>= 1) { if (tid < s) red[tid] += red[tid + s]; __syncthreads(); }
  float mu = red[0] * (1.f / 512.f);
  __syncthreads();
  float d0 = v0 - mu, d1 = v1 - mu;
  red[tid] = d0 * d0 + d1 * d1; __syncthreads();
  for (int s = 128; s; s >>= 1) { if (tid < s) red[tid] += red[tid + s]; __syncthreads(); }
  float rstd = rsqrtf(red[0] * (1.f / 512.f) + 1e-5f);
  float* o = Outp + (size_t)row * 512;
  o[tid]       = d0 * rstd * gamma[tid]       + beta[tid];
  o[tid + 256] = d1 * rstd * gamma[tid + 256] + beta[tid + 256];
}

// ---------------------------------------------------------------------------
extern "C" void kernel_launch(void* const* d_in, const int* in_sizes, int n_in,
                              void* d_out, int out_size, void* d_ws, size_t ws_size,
                              hipStream_t stream) {
  const float* x     = (const float*)d_in[0];
  const float* Wq    = (const float*)d_in[1];
  const float* bq    = (const float*)d_in[2];
  const float* Wk    = (const float*)d_in[3];
  const float* bk    = (const float*)d_in[4];
  const float* Wv    = (const float*)d_in[5];
  const float* bv    = (const float*)d_in[6];
  const float* wpq   = (const float*)d_in[7];
  const float* wpk   = (const float*)d_in[8];
  const float* wpv   = (const float*)d_in[9];
  const float* wpx   = (const float*)d_in[10];
  const float* Wd    = (const float*)d_in[11];
  const float* bd    = (const float*)d_in[12];
  const float* gamma = (const float*)d_in[13];
  const float* beta  = (const float*)d_in[14];
  float* outp = (float*)d_out;

  auto rnd = [](size_t b) { return (b + 255) / 256 * 256; };
  const size_t persist =
      rnd((size_t)LP * 512 * 4) +            // embz
      rnd((size_t)Bb * Ll * 512 * 2) +       // xbf
      4 * rnd((size_t)512 * 2048 * 2) +      // wpxT + wpqT/wpkT/wpvT
      3 * rnd((size_t)8 * 512 * 512 * 2) +   // WqT/WkT/WvT
      rnd((size_t)512 * 4096 * 2) +          // WdB
      rnd((size_t)16 * LP * 512 * 2) +       // Outb
      rnd((size_t)2 * LP * 512 * 2) +        // PX
      rnd((size_t)2 * LL2 * 512 * 4) +       // Y
      rnd((size_t)16 * LP * 4);              // cfx
  auto chpart = [&](int CH) {
    return rnd((size_t)3 * CH * 512 * 2048 * 2) + rnd((size_t)3 * CH * 512 * 4) +
           3 * rnd((size_t)2 * CH * LP * 512 * 2);
  };
  const size_t lgbytes = rnd((size_t)LP * LP * 4);
  int CH = 8;
  while (CH > 1 && persist + chpart(CH) + lgbytes > ws_size) CH >>= 1;
  if (persist + chpart(CH) + lgbytes > ws_size) return;
  int NA = (int)((ws_size - persist - chpart(CH)) / lgbytes);
  if (NA > 2 * CH) NA = 2 * CH;
  int nc = 8 / CH;

  char* w = (char*)d_ws;
  auto alloc = [&](size_t bytes) { char* p = w; w += (bytes + 255) / 256 * 256; return p; };
  float* embz = (float*)alloc((size_t)LP * 512 * 4);
  short* xbf  = (short*)alloc((size_t)Bb * Ll * 512 * 2);
  short* wpxT = (short*)alloc((size_t)512 * 2048 * 2);
  short* wpqT = (short*)alloc((size_t)512 * 2048 * 2);
  short* wpkT = (short*)alloc((size_t)512 * 2048 * 2);
  short* wpvT = (short*)alloc((size_t)512 * 2048 * 2);
  short* WqT  = (short*)alloc((size_t)8 * 512 * 512 * 2);
  short* WkT  = (short*)alloc((size_t)8 * 512 * 512 * 2);
  short* WvT  = (short*)alloc((size_t)8 * 512 * 512 * 2);
  short* WdB  = (short*)alloc((size_t)512 * 4096 * 2);
  short* Outb = (short*)alloc((size_t)16 * LP * 512 * 2);
  short* PX   = (short*)alloc((size_t)2 * LP * 512 * 2);
  float* Y    = (float*)alloc((size_t)2 * LL2 * 512 * 4);
  float* cfx  = (float*)alloc((size_t)16 * LP * 4);
  short* Weff = (short*)alloc((size_t)3 * CH * 512 * 2048 * 2);
  float* beff = (float*)alloc((size_t)3 * CH * 512 * 4);
  short* PQ   = (short*)alloc((size_t)2 * CH * LP * 512 * 2);
  short* PKf  = (short*)alloc((size_t)2 * CH * LP * 512 * 2);
  short* PVt  = (short*)alloc((size_t)2 * CH * LP * 512 * 2);
  float* Lg   = (float*)alloc((size_t)NA * LP * LP * 4);

  dim3 blk(256);
  emb_kernel<<<dim3((LP * 512 + 255) / 256), blk, 0, stream>>>(embz);
  cvt_kernel<<<dim3((Bb * Ll * 512 / 4 + 255) / 256), blk, 0, stream>>>(x, xbf, Bb * Ll * 512 / 4);
  wpxt_kernel<<<dim3(4096), blk, 0, stream>>>(wpx, wpxT);
  wpxt_kernel<<<dim3(4096), blk, 0, stream>>>(wpq, wpqT);
  wpxt_kernel<<<dim3(4096), blk, 0, stream>>>(wpk, wpkT);
  wpxt_kernel<<<dim3(4096), blk, 0, stream>>>(wpv, wpvT);
  tr_w_kernel<<<dim3(8, 8, 8), blk, 0, stream>>>(Wq, WqT);
  tr_w_kernel<<<dim3(8, 8, 8), blk, 0, stream>>>(Wk, WkT);
  tr_w_kernel<<<dim3(8, 8, 8), blk, 0, stream>>>(Wv, WvT);
  cvt_kernel<<<dim3((512 * 4096 / 4 + 255) / 256), blk, 0, stream>>>(Wd, WdB, 512 * 4096 / 4);
  px_pool<<<dim3(50, 8), blk, 0, stream>>>(xbf, wpxT, PX);
  pxcls_kernel<<<dim3(2), dim3(512), 0, stream>>>(x, PX);

  for (int c = 0; c < nc; ++c) {
    int h0 = c * CH;
    weff128<<<dim3(4, 4, 12 * CH), blk, 0, stream>>>(wpqT, wpkT, wpvT, WqT, WkT, WvT,
                                                     h0, CH, Weff);
    beff_fused<<<dim3(3, CH), blk, 0, stream>>>(bq, bk, bv, wpq, wpk, wpv, h0, CH, beff);
    pool128x2<<<dim3(13 * 12 * CH), blk, 0, stream>>>(xbf, Weff, beff, embz,
                                                      PQ, PKf, PVt, CH);
    cls_fast<<<dim3(128, 3, 2 * CH), blk, 0, stream>>>(xbf, Wq, bq, Wk, bk, Wv, bv,
                                                       h0, CH, PQ, PKf, PVt);
    for (int a0 = 0; a0 < 2 * CH; a0 += NA) {
      int na = (2 * CH - a0) < NA ? (2 * CH - a0) : NA;
      cfix_kernel<<<dim3(400, na), blk, 0, stream>>>(PQ, embz, a0, cfx);
      logits128<<<dim3(13, 13, na), blk, 0, stream>>>(PQ, PKf, cfx, a0, Lg);
      softmax_kernel<<<dim3(LL2, na), blk, 0, stream>>>(Lg);
      av128<<<dim3(13, 4, na), blk, 0, stream>>>(Lg, PVt, PQ, Outb, h0, CH, a0);
    }
  }

  final128<<<dim3(25, 4), blk, 0, stream>>>(Outb, WdB, bd, PX, Y);
  ln_kernel<<<dim3(Bb * LL2), blk, 0, stream>>>(Y, gamma, beta, outp);
}

// Round 9
// 918.132 us; speedup vs baseline: 2.9235x; 1.1740x over previous
//
#include <hip/hip_runtime.h>
#include <hip/hip_bf16.h>
#include <cstdint>
#include <cstddef>

typedef __hip_bfloat16 bf16;
typedef __attribute__((ext_vector_type(8))) short short8;   // 8 bf16 in 4 VGPRs
typedef __attribute__((ext_vector_type(4))) short short4v;
typedef __attribute__((ext_vector_type(4))) float f32x4;
#define DEVI __device__ __forceinline__

constexpr int Bb = 2, Ll = 6273, Pp = 1568, LL2 = 1569, LP = 1600;
constexpr float QK_SCALE = 0.04419417382415922f;  // 512^-0.5

DEVI short f2bs(float f) {
  __hip_bfloat16 h = __float2bfloat16(f);
  return __builtin_bit_cast(short, h);
}
DEVI float bs2f(short s) {
  __hip_bfloat16 h = __builtin_bit_cast(__hip_bfloat16, s);
  return __bfloat162float(h);
}

// async global->LDS, 16B per lane. LDS dest = wave-uniform base + lane*16.
DEVI void gload16(const short* g, short* l) {
  __builtin_amdgcn_global_load_lds(
      (const __attribute__((address_space(1))) void*)g,
      (__attribute__((address_space(3))) void*)l,
      16, 0, 0);
}

// ===========================================================================
// 128x128 MFMA tile core, BK=64, 256 threads = 4 waves in 2x2 (each 64x64 via
// 4x4 frags of mfma_f32_16x16x32_bf16). PROVEN schedule (R1, 1056us):
// single-buffer stage -> __syncthreads -> mma -> __syncthreads.
// Register ledger (R5-R8, settled):
//  - no __launch_bounds__ => 128-reg cap => wide acc spills (R5/R6).
//  - __launch_bounds__(256) uncapped => 280 regs => 1 blk/CU latency-bound (R7).
//  - __launch_bounds__(256,2) + b-shared mma128_dual => 96 VGPR + 128 AGPR
//    = 224 <= 256 => 2 waves/SIMD, no spill (R8: WRITE 96MB, 560 TF). This is
//    the structure's plateau; R9 stops touching the GEMM schedule.
// 16B-slot XOR swizzle (slot ^= row&7) -> conflict-free b128 reads.
// Staging: global_load_lds LINEAR dest + inverse-swizzled per-lane global
// SOURCE (rule 21). C/D layout per m89: col=lane&15, row=quad*4+e.
// ===========================================================================
constexpr int BK = 64;

DEVI int sw_idx(int row, int slot) {            // slot = 16B unit (8 shorts)
  return row * BK + (((slot) ^ (row & 7)) << 3);
}

DEVI void mma128(const short* As, const short* Bs, int lane, int wr, int wc,
                 f32x4 (&acc)[4][4]) {
  int m = lane & 15, quad = lane >> 4;
  #pragma unroll
  for (int kh = 0; kh < 2; ++kh) {
    int slot = kh * 4 + quad;
    short8 a[4], b[4];
    #pragma unroll
    for (int i = 0; i < 4; ++i) {
      int row = wr * 64 + i * 16 + m;
      a[i] = *(const short8*)(As + sw_idx(row, slot));
    }
    #pragma unroll
    for (int j = 0; j < 4; ++j) {
      int row = wc * 64 + j * 16 + m;
      b[j] = *(const short8*)(Bs + sw_idx(row, slot));
    }
    #pragma unroll
    for (int i = 0; i < 4; ++i)
      #pragma unroll
      for (int j = 0; j < 4; ++j)
        acc[i][j] = __builtin_amdgcn_mfma_f32_16x16x32_bf16(a[i], b[j], acc[i][j], 0, 0, 0);
  }
}

// Dual-A core: loads shared b[4] ONCE for two A-tiles.
DEVI void mma128_dual(const short* As0, const short* As1, const short* Bs,
                      int lane, int wr, int wc,
                      f32x4 (&acc0)[4][4], f32x4 (&acc1)[4][4]) {
  int m = lane & 15, quad = lane >> 4;
  #pragma unroll
  for (int kh = 0; kh < 2; ++kh) {
    int slot = kh * 4 + quad;
    short8 b[4];
    #pragma unroll
    for (int j = 0; j < 4; ++j)
      b[j] = *(const short8*)(Bs + sw_idx(wc * 64 + j * 16 + m, slot));
    #pragma unroll
    for (int i = 0; i < 4; ++i) {
      int row = wr * 64 + i * 16 + m;
      short8 a0 = *(const short8*)(As0 + sw_idx(row, slot));
      short8 a1 = *(const short8*)(As1 + sw_idx(row, slot));
      #pragma unroll
      for (int j = 0; j < 4; ++j) {
        acc0[i][j] = __builtin_amdgcn_mfma_f32_16x16x32_bf16(a0, b[j], acc0[i][j], 0, 0, 0);
        acc1[i][j] = __builtin_amdgcn_mfma_f32_16x16x32_bf16(a1, b[j], acc1[i][j], 0, 0, 0);
      }
    }
  }
}

// ---------------------------------------------------------------------------
__global__ void emb_kernel(float* __restrict__ embz) {
  int idx = blockIdx.x * 256 + threadIdx.x;
  if (idx >= LP * 512) return;
  int p = idx >> 9, d = idx & 511;
  float v = 0.f;
  if (p > 0 && p < LL2) {
    int pb = p - 1;
    int t = pb / 196, r = pb % 196;
    int h = r / 14, ww = r % 14;
    int pos, j, half;
    if (d < 170)      { pos = t;  j = d;       half = 85; }
    else if (d < 340) { pos = h;  j = d - 170; half = 85; }
    else              { pos = ww; j = d - 340; half = 86; }
    int jj = (j < half) ? j : (j - half);
    float omega = powf(10000.f, -(float)jj / (float)half);
    float ang = (float)pos * omega;
    v = (j < half) ? sinf(ang) : cosf(ang);
  }
  embz[idx] = v;
}

// f32 -> bf16 bulk convert, 4 elements/thread
__global__ void cvt_kernel(const float* __restrict__ src, short* __restrict__ dst, int n4) {
  int idx = blockIdx.x * 256 + threadIdx.x;
  if (idx >= n4) return;
  float4 v = *(const float4*)(src + (size_t)idx * 4);
  short4v o = { f2bs(v.x), f2bs(v.y), f2bs(v.z), f2bs(v.w) };
  *(short4v*)(dst + (size_t)idx * 4) = o;
}

// wpT[n][tap*512+k] = bf16(wp[n*2048 + k*4 + tap])  (works for wpx/wpq/wpk/wpv)
__global__ void wpxt_kernel(const float* __restrict__ wp, short* __restrict__ wpT) {
  int idx = blockIdx.x * 256 + threadIdx.x;
  if (idx >= 512 * 2048) return;
  int n = idx >> 11, rem = idx & 2047, tap = rem >> 9, k = rem & 511;
  wpT[idx] = f2bs(wp[n * 2048 + k * 4 + tap]);
}

// WT[h][k][i] = bf16(W[(h*512+i)*512 + k])
__global__ void tr_w_kernel(const float* __restrict__ W, short* __restrict__ WT) {
  __shared__ float Ws[64][65];
  int i0 = blockIdx.x * 64, k0 = blockIdx.y * 64, h = blockIdx.z;
  int tid = threadIdx.x;
  int r = tid >> 2, c0 = (tid & 3) * 16;
  const float* src = W + ((size_t)(h * 512 + i0 + r)) * 512 + k0 + c0;
  #pragma unroll
  for (int j = 0; j < 16; ++j) Ws[r][c0 + j] = src[j];
  __syncthreads();
  short* dst = WT + ((size_t)(h * 512 + k0 + r)) * 512 + i0 + c0;
  #pragma unroll
  for (int j = 0; j < 16; ++j) dst[j] = f2bs(Ws[c0 + j][r]);
}

// ===========================================================================
// weff128: Weff[(mat*CH+ch)*512+n][tap*512+k] = sum_i wpT[n][tap*512+i]*WT[h][k][i]
// grid (4, 4, 12*CH) — R1 single-buffer schedule
// ===========================================================================
__global__ void weff128(const short* __restrict__ wpqT, const short* __restrict__ wpkT,
                        const short* __restrict__ wpvT,
                        const short* __restrict__ WqT, const short* __restrict__ WkT,
                        const short* __restrict__ WvT,
                        int h0, int CH, short* __restrict__ Weff) {
  __shared__ __align__(16) short As[128 * BK];
  __shared__ __align__(16) short Bs[128 * BK];
  int n0 = blockIdx.x * 128, k0 = blockIdx.y * 128;
  int z = blockIdx.z;
  int mat = z / (4 * CH), rem = z % (4 * CH);
  int ch = rem >> 2, tap = rem & 3;
  const short* wpT = mat == 0 ? wpqT : (mat == 1 ? wpkT : wpvT);
  const short* WT  = mat == 0 ? WqT  : (mat == 1 ? WkT  : WvT);
  int h = h0 + ch;
  int tid = threadIdx.x, lane = tid & 63, w = tid >> 6, wr = w >> 1, wc = w & 1;
  int rbase = tid >> 3;
  int ss = ((tid & 7) ^ (rbase & 7)) << 3;   // pre-swizzled source slot (shorts)
  f32x4 acc[4][4] = {};
  for (int kq = 0; kq < 512; kq += BK) {
    #pragma unroll
    for (int p = 0; p < 4; ++p) {
      int row = rbase + 32 * p;
      gload16(wpT + (size_t)(n0 + row) * 2048 + tap * 512 + kq + ss,
              As + (32 * p + 8 * w) * BK);
      gload16(WT + ((size_t)(h * 512 + k0 + row)) * 512 + kq + ss,
              Bs + (32 * p + 8 * w) * BK);
    }
    __syncthreads();
    mma128(As, Bs, lane, wr, wc, acc);
    __syncthreads();
  }
  int m = lane & 15, quad = lane >> 4;
  size_t base = ((size_t)(mat * CH + ch) * 512) * 2048 + tap * 512;
  #pragma unroll
  for (int i = 0; i < 4; ++i)
    #pragma unroll
    for (int j = 0; j < 4; ++j)
      #pragma unroll
      for (int e = 0; e < 4; ++e) {
        int n = n0 + wr * 64 + i * 16 + quad * 4 + e;
        int k = k0 + wc * 64 + j * 16 + m;
        Weff[base + (size_t)n * 2048 + k] = f2bs(acc[i][j][e]);
      }
}

// beff[(mat*CH+ch)][n] = sum_i bias[i] * sum_taps wp[n][i][tap]
// R9: wave-per-n, lanes split i -> coalesced 128B/lane rows (old version was
// thread-per-n with 8KB inter-lane stride = fully uncoalesced, 24 blocks).
// grid (3, CH, 4): z = 128-wide n-quarter. 256 thr = 4 waves, n = n0+wv+4*it.
__global__ void beff_fused(const float* __restrict__ bq, const float* __restrict__ bk,
                           const float* __restrict__ bv,
                           const float* __restrict__ wpq, const float* __restrict__ wpk,
                           const float* __restrict__ wpv,
                           int h0, int CH, float* __restrict__ beff) {
  int mat = blockIdx.x, ch = blockIdx.y, n0 = blockIdx.z * 128;
  int wv = threadIdx.x >> 6, lane = threadIdx.x & 63;
  const float* bias = mat == 0 ? bq : (mat == 1 ? bk : bv);
  const float* wp = mat == 0 ? wpq : (mat == 1 ? wpk : wpv);
  // preload this lane's 8 bias values (i = lane*8 .. lane*8+7)
  float bi[8];
  #pragma unroll
  for (int t = 0; t < 8; ++t) bi[t] = bias[(h0 + ch) * 512 + lane * 8 + t];
  for (int n = n0 + wv; n < n0 + 128; n += 4) {
    const float* row = wp + (size_t)n * 2048 + lane * 32;  // 8 i x 4 taps, contiguous
    float s = 0.f;
    #pragma unroll
    for (int t = 0; t < 8; ++t) {
      float4 v = *(const float4*)(row + t * 4);
      s += bi[t] * (v.x + v.y + v.z + v.w);
    }
    #pragma unroll
    for (int off = 32; off; off >>= 1) s += __shfl_down(s, off, 64);
    if (lane == 0) beff[(mat * CH + ch) * 512 + n] = s;
  }
}

// ===========================================================================
// pool128x2: one B-tile (128 cols) shared by TWO A-tiles per block.
// R9: PX folded in as mat==3 (B = wpxT directly, no bias) — same GEMM shape,
// kills the slow old px_pool kernel. NT = 12*CH + 4.
// __launch_bounds__(256,2): 224 regs/wave, 2 waves/SIMD, no spill (R8).
// grid 13*NT, bijective XCD swizzle (m204).
// ===========================================================================
__global__ void __launch_bounds__(256, 2)
pool128x2(const short* __restrict__ xbf, const short* __restrict__ Weff,
          const short* __restrict__ wpxT,
          const float* __restrict__ beff, const float* __restrict__ embz,
          short* __restrict__ PQ, short* __restrict__ PKf,
          short* __restrict__ PVt, short* __restrict__ PX, int CH) {
  int NT = 12 * CH + 4;
  int nwg = 13 * NT;
  int bid = blockIdx.x;
  int q8 = nwg >> 3, r8 = nwg & 7;
  int xcd = bid & 7, lin = bid >> 3;
  int wgid = (xcd < r8 ? xcd * (q8 + 1) : r8 * (q8 + 1) + (xcd - r8) * q8) + lin;
  int nt = wgid % NT, pr = wgid / NT;        // pr in 0..12
  int mb0 = pr * 2, mb1 = pr * 2 + 1;        // two m-tiles share one B-tile
  int mt0 = mb0 % 13, b0 = mb0 / 13;
  int mt1 = mb1 % 13, b1 = mb1 / 13;
  int mat, ch, n0t;
  const short* Bsrc;
  if (nt < 12 * CH) {
    mat = nt / (4 * CH); ch = (nt >> 2) % CH; n0t = (nt & 3) * 128;
    Bsrc = Weff + (size_t)nt * 128 * 2048;
  } else {
    mat = 3; ch = 0; n0t = (nt - 12 * CH) * 128;
    Bsrc = wpxT + (size_t)n0t * 2048;
  }

  __shared__ __align__(16) short As0[128 * BK];
  __shared__ __align__(16) short As1[128 * BK];
  __shared__ __align__(16) short Bs[128 * BK];
  int tid = threadIdx.x, lane = tid & 63, w = tid >> 6, wr = w >> 1, wc = w & 1;
  int rbase = tid >> 3;
  int ss = ((tid & 7) ^ (rbase & 7)) << 3;
  // prologue: pooled-position source bases (in shorts) for the staged rows
  int srcA0[4], srcA1[4];
  #pragma unroll
  for (int p = 0; p < 4; ++p) {
    int row = rbase + 32 * p;
    int pb0 = mt0 * 128 + row; if (pb0 > Pp - 1) pb0 = Pp - 1;
    int t3 = pb0 / 196, rm = pb0 % 196, h2 = rm / 14, w2 = rm % 14;
    srcA0[p] = b0 * (Ll * 512) + (1 + t3 * 784 + h2 * 56 + w2 * 2) * 512;
    int pb1 = mt1 * 128 + row; if (pb1 > Pp - 1) pb1 = Pp - 1;
    int t3b = pb1 / 196, rmb = pb1 % 196, h2b = rmb / 14, w2b = rmb % 14;
    srcA1[p] = b1 * (Ll * 512) + (1 + t3b * 784 + h2b * 56 + w2b * 2) * 512;
  }

  f32x4 acc0[4][4] = {};
  f32x4 acc1[4][4] = {};
  for (int kq = 0; kq < 2048; kq += BK) {
    int tap = kq >> 9, koff = kq & 511;
    int tr = ((tap & 1) + (tap >> 1) * 28) * 512;   // taprow {0,1,28,29} in shorts
    #pragma unroll
    for (int p = 0; p < 4; ++p) {
      int row = rbase + 32 * p;
      gload16(xbf + (size_t)(srcA0[p] + tr + koff + ss), As0 + (32 * p + 8 * w) * BK);
      gload16(xbf + (size_t)(srcA1[p] + tr + koff + ss), As1 + (32 * p + 8 * w) * BK);
      gload16(Bsrc + (size_t)row * 2048 + kq + ss, Bs + (32 * p + 8 * w) * BK);
    }
    __syncthreads();
    mma128_dual(As0, As1, Bs, lane, wr, wc, acc0, acc1);
    __syncthreads();
  }
  int m = lane & 15, quad = lane >> 4;
  int bb = (mat < 3 ? (mat * CH + ch) : 0) * 512;
  // epilogue for acc0
  {
    int cg = b0 * CH + ch;
    #pragma unroll
    for (int i = 0; i < 4; ++i)
      #pragma unroll
      for (int j = 0; j < 4; ++j)
        #pragma unroll
        for (int e = 0; e < 4; ++e) {
          int row = wr * 64 + i * 16 + quad * 4 + e;
          int pb = mt0 * 128 + row;
          if (pb >= Pp) continue;
          int tok = pb + 1;
          int n = n0t + wc * 64 + j * 16 + m;
          float bv = (mat < 3) ? beff[bb + n] : 0.f;
          float val = acc0[i][j][e] + bv;
          if (mat == 0)      PQ[((size_t)cg * LP + tok) * 512 + n] = f2bs(val);
          else if (mat == 1) PKf[((size_t)cg * LP + tok) * 512 + n] =
                                 f2bs(val * QK_SCALE + embz[(size_t)tok * 512 + n]);
          else if (mat == 2) PVt[((size_t)cg * 512 + n) * LP + tok] = f2bs(val);
          else               PX[((size_t)b0 * LP + tok) * 512 + n] = f2bs(val);
        }
  }
  // epilogue for acc1
  {
    int cg = b1 * CH + ch;
    #pragma unroll
    for (int i = 0; i < 4; ++i)
      #pragma unroll
      for (int j = 0; j < 4; ++j)
        #pragma unroll
        for (int e = 0; e < 4; ++e) {
          int row = wr * 64 + i * 16 + quad * 4 + e;
          int pb = mt1 * 128 + row;
          if (pb >= Pp) continue;
          int tok = pb + 1;
          int n = n0t + wc * 64 + j * 16 + m;
          float bv = (mat < 3) ? beff[bb + n] : 0.f;
          float val = acc1[i][j][e] + bv;
          if (mat == 0)      PQ[((size_t)cg * LP + tok) * 512 + n] = f2bs(val);
          else if (mat == 1) PKf[((size_t)cg * LP + tok) * 512 + n] =
                                 f2bs(val * QK_SCALE + embz[(size_t)tok * 512 + n]);
          else if (mat == 2) PVt[((size_t)cg * 512 + n) * LP + tok] = f2bs(val);
          else               PX[((size_t)b1 * LP + tok) * 512 + n] = f2bs(val);
        }
  }
}

// cls row (token 0): one wave per output dot product. grid(128, 3, 2CH)
__global__ void cls_fast(const short* __restrict__ xbf,
                         const float* __restrict__ Wq, const float* __restrict__ bq,
                         const float* __restrict__ Wk, const float* __restrict__ bk,
                         const float* __restrict__ Wv, const float* __restrict__ bv,
                         int h0, int CH,
                         short* __restrict__ PQ, short* __restrict__ PKf,
                         short* __restrict__ PVt) {
  int cg = blockIdx.z, mat = blockIdx.y;
  int wv = threadIdx.x >> 6, lane = threadIdx.x & 63;
  int n = blockIdx.x * 4 + wv;
  int b = cg / CH, h = h0 + cg % CH;
  const float* W = mat == 0 ? Wq : (mat == 1 ? Wk : Wv);
  const float* bias = mat == 0 ? bq : (mat == 1 ? bk : bv);
  const short* xr = xbf + (size_t)b * Ll * 512;
  const float* wr = W + ((size_t)(h * 512 + n)) * 512;
  float s = 0.f;
  #pragma unroll
  for (int j = 0; j < 8; ++j) {
    int k = lane * 8 + j;
    s += bs2f(xr[k]) * wr[k];
  }
  #pragma unroll
  for (int off = 32; off; off >>= 1) s += __shfl_down(s, off, 64);
  if (lane == 0) {
    s += bias[h * 512 + n];
    if (mat == 0)      PQ[((size_t)cg * LP) * 512 + n] = f2bs(s);
    else if (mat == 1) PKf[((size_t)cg * LP) * 512 + n] = f2bs(s * QK_SCALE);
    else               PVt[((size_t)cg * 512 + n) * LP] = f2bs(s);
  }
}

// PX cls row
__global__ void pxcls_kernel(const float* __restrict__ x, short* __restrict__ PX) {
  int b = blockIdx.x, n = threadIdx.x;
  PX[(size_t)b * LP * 512 + n] = f2bs(x[(size_t)b * Ll * 512 + n]);
}

// cfx[cg][kt] = dot(PQ[cg,0,:], embz[kt,:])
__global__ void cfix_kernel(const short* __restrict__ PQ, const float* __restrict__ embz,
                            int a0, float* __restrict__ cfx) {
  int cg = a0 + blockIdx.y;
  int wv = threadIdx.x >> 6, lane = threadIdx.x & 63;
  int kt = blockIdx.x * 4 + wv;
  if (kt >= LP) return;
  int ktc = kt < LL2 ? kt : (LL2 - 1);
  const short* q0 = PQ + (size_t)cg * LP * 512;
  const float* e = embz + (size_t)ktc * 512;
  float s = 0.f;
  #pragma unroll
  for (int j = 0; j < 8; ++j) {
    int d = lane * 8 + j;
    s += bs2f(q0[d]) * e[d];
  }
  #pragma unroll
  for (int off = 32; off; off >>= 1) s += __shfl_down(s, off, 64);
  if (lane == 0) cfx[(size_t)cg * LP + kt] = s;
}

// ===========================================================================
// logits128: Lg[z][q][kt] = PQ[cg] . PKf[cg]; row0 -= cfx. grid (13,13,na)
// ===========================================================================
__global__ void logits128(const short* __restrict__ PQ, const short* __restrict__ PKf,
                          const float* __restrict__ cfx, int a0, float* __restrict__ Lg) {
  __shared__ __align__(16) short As[128 * BK];
  __shared__ __align__(16) short Bs[128 * BK];
  int q0 = blockIdx.x * 128, k0 = blockIdx.y * 128, z = blockIdx.z;
  int cg = a0 + z;
  int tid = threadIdx.x, lane = tid & 63, w = tid >> 6, wr = w >> 1, wc = w & 1;
  int rbase = tid >> 3;
  int ss = ((tid & 7) ^ (rbase & 7)) << 3;
  const short* Aq = PQ + (size_t)cg * LP * 512;
  const short* Bk = PKf + (size_t)cg * LP * 512;
  f32x4 acc[4][4] = {};
  for (int kq = 0; kq < 512; kq += BK) {
    #pragma unroll
    for (int p = 0; p < 4; ++p) {
      int row = rbase + 32 * p;
      int ar = q0 + row; if (ar > LL2 - 1) ar = LL2 - 1;
      int br = k0 + row; if (br > LL2 - 1) br = LL2 - 1;
      gload16(Aq + (size_t)ar * 512 + kq + ss, As + (32 * p + 8 * w) * BK);
      gload16(Bk + (size_t)br * 512 + kq + ss, Bs + (32 * p + 8 * w) * BK);
    }
    __syncthreads();
    mma128(As, Bs, lane, wr, wc, acc);
    __syncthreads();
  }
  int m = lane & 15, quad = lane >> 4;
  float* lg = Lg + (size_t)z * LP * LP;
  const float* cf = cfx + (size_t)cg * LP;
  #pragma unroll
  for (int i = 0; i < 4; ++i)
    #pragma unroll
    for (int j = 0; j < 4; ++j)
      #pragma unroll
      for (int e = 0; e < 4; ++e) {
        int q = q0 + wr * 64 + i * 16 + quad * 4 + e;
        int kt = k0 + wc * 64 + j * 16 + m;
        if (q >= LP || kt >= LP) continue;
        float val = acc[i][j][e];
        if (q == 0) val -= cf[kt];
        lg[(size_t)q * LP + kt] = val;
      }
}

// softmax: wave-per-row single-pass (R9). 7 masked float4 loads in regs,
// two shfl reductions, short4 stores (covers the [LL2,LP) zero-pad).
// grid (ceil(LL2/4), na), 256 thr = 4 waves = 4 rows/block.
__global__ void softmax_kernel(float* __restrict__ Lg) {
  int z = blockIdx.y;
  int wv = threadIdx.x >> 6, lane = threadIdx.x & 63;
  int q = blockIdx.x * 4 + wv;
  if (q >= LL2) return;
  float* p = Lg + ((size_t)z * LP + q) * LP;
  float vbuf[28];
  float mx = -1e30f;
  #pragma unroll
  for (int it = 0; it < 7; ++it) {
    int j = it * 256 + lane * 4;
    float4 v;
    if (j < LP) v = *(const float4*)(p + j);
    else        v = make_float4(0.f, 0.f, 0.f, 0.f);
    #pragma unroll
    for (int e = 0; e < 4; ++e) {
      float f = (&v.x)[e];
      float masked = ((j + e) < LL2) ? f : -1e30f;
      vbuf[it * 4 + e] = masked;
      mx = fmaxf(mx, masked);
    }
  }
  #pragma unroll
  for (int off = 32; off; off >>= 1) mx = fmaxf(mx, __shfl_xor(mx, off, 64));
  float sum = 0.f;
  #pragma unroll
  for (int it = 0; it < 7; ++it)
    #pragma unroll
    for (int e = 0; e < 4; ++e) {
      float ev = __expf(vbuf[it * 4 + e] - mx);   // masked -> exp(-huge) = 0
      vbuf[it * 4 + e] = ev;
      sum += ev;
    }
  #pragma unroll
  for (int off = 32; off; off >>= 1) sum += __shfl_xor(sum, off, 64);
  float inv = 1.f / sum;
  short* o = (short*)p;
  #pragma unroll
  for (int it = 0; it < 7; ++it) {
    int j = it * 256 + lane * 4;
    if (j < LP) {
      short4v ov = { f2bs(vbuf[it * 4 + 0] * inv), f2bs(vbuf[it * 4 + 1] * inv),
                     f2bs(vbuf[it * 4 + 2] * inv), f2bs(vbuf[it * 4 + 3] * inv) };
      *(short4v*)(o + j) = ov;
    }
  }
}

// ===========================================================================
// av128: Outb[gg][q][n] = attn @ PVt + (q==0?1:2)*PQ. grid (13,4,na)
// ===========================================================================
__global__ void av128(const float* __restrict__ Lg, const short* __restrict__ PVt,
                      const short* __restrict__ PQ, short* __restrict__ Outb,
                      int h0, int CH, int a0) {
  __shared__ __align__(16) short As[128 * BK];
  __shared__ __align__(16) short Bs[128 * BK];
  int q0 = blockIdx.x * 128, n0 = blockIdx.y * 128, z = blockIdx.z;
  int cg = a0 + z;
  int b = cg / CH, gg = b * 8 + h0 + cg % CH;
  int tid = threadIdx.x, lane = tid & 63, w = tid >> 6, wr = w >> 1, wc = w & 1;
  int rbase = tid >> 3;
  int ss = ((tid & 7) ^ (rbase & 7)) << 3;
  const short* Aat = (const short*)(Lg + (size_t)z * LP * LP);  // bf16 rows, stride 2*LP
  const short* Bv = PVt + (size_t)cg * 512 * LP;
  f32x4 acc[4][4] = {};
  for (int kq = 0; kq < LP; kq += BK) {
    #pragma unroll
    for (int p = 0; p < 4; ++p) {
      int row = rbase + 32 * p;
      int ar = q0 + row; if (ar > LP - 1) ar = LP - 1;
      gload16(Aat + (size_t)ar * (2 * LP) + kq + ss, As + (32 * p + 8 * w) * BK);
      gload16(Bv + (size_t)(n0 + row) * LP + kq + ss, Bs + (32 * p + 8 * w) * BK);
    }
    __syncthreads();
    mma128(As, Bs, lane, wr, wc, acc);
    __syncthreads();
  }
  int m = lane & 15, quad = lane >> 4;
  #pragma unroll
  for (int i = 0; i < 4; ++i)
    #pragma unroll
    for (int j = 0; j < 4; ++j)
      #pragma unroll
      for (int e = 0; e < 4; ++e) {
        int q = q0 + wr * 64 + i * 16 + quad * 4 + e;
        if (q >= LL2) continue;
        int n = n0 + wc * 64 + j * 16 + m;
        float res = bs2f(PQ[((size_t)cg * LP + q) * 512 + n]);
        float val = acc[i][j][e] + (q == 0 ? 1.f : 2.f) * res;
        Outb[((size_t)gg * LP + q) * 512 + n] = f2bs(val);
      }
}

// ===========================================================================
// final128: Y = stacked @ Wd^T + bd + PX. grid (25, 4). M=3138 flat (b,q).
// ===========================================================================
__global__ void final128(const short* __restrict__ Outb, const short* __restrict__ WdB,
                         const float* __restrict__ bd, const short* __restrict__ PX,
                         float* __restrict__ Y) {
  __shared__ __align__(16) short As[128 * BK];
  __shared__ __align__(16) short Bs[128 * BK];
  int mf0 = blockIdx.x * 128, n0 = blockIdx.y * 128;
  int tid = threadIdx.x, lane = tid & 63, w = tid >> 6, wr = w >> 1, wc = w & 1;
  int rbase = tid >> 3;
  int ss = ((tid & 7) ^ (rbase & 7)) << 3;
  const int M = Bb * LL2;  // 3138
  int brow[4], qrow[4];
  #pragma unroll
  for (int p = 0; p < 4; ++p) {
    int mf = mf0 + rbase + 32 * p; if (mf > M - 1) mf = M - 1;
    brow[p] = mf / LL2; qrow[p] = mf % LL2;
  }
  f32x4 acc[4][4] = {};
  for (int kq = 0; kq < 4096; kq += BK) {
    int hh = kq >> 9, koff = kq & 511;
    #pragma unroll
    for (int p = 0; p < 4; ++p) {
      int row = rbase + 32 * p;
      gload16(Outb + ((size_t)(brow[p] * 8 + hh) * LP + qrow[p]) * 512 + koff + ss,
              As + (32 * p + 8 * w) * BK);
      gload16(WdB + (size_t)(n0 + row) * 4096 + kq + ss,
              Bs + (32 * p + 8 * w) * BK);
    }
    __syncthreads();
    mma128(As, Bs, lane, wr, wc, acc);
    __syncthreads();
  }
  int m = lane & 15, quad = lane >> 4;
  #pragma unroll
  for (int i = 0; i < 4; ++i)
    #pragma unroll
    for (int j = 0; j < 4; ++j)
      #pragma unroll
      for (int e = 0; e < 4; ++e) {
        int mf = mf0 + wr * 64 + i * 16 + quad * 4 + e;
        if (mf >= M) continue;
        int b2 = mf / LL2, q2 = mf % LL2;
        int dm = n0 + wc * 64 + j * 16 + m;
        float val = acc[i][j][e] + bd[dm] + bs2f(PX[((size_t)b2 * LP + q2) * 512 + dm]);
        Y[(size_t)mf * 512 + dm] = val;
      }
}

// LayerNorm over 512
__global__ void ln_kernel(const float* __restrict__ Y, const float* __restrict__ gamma,
                          const float* __restrict__ beta, float* __restrict__ Outp) {
  int row = blockIdx.x;
  const float* y = Y + (size_t)row * 512;
  __shared__ float red[256];
  int tid = threadIdx.x;
  float v0 = y[tid], v1 = y[tid + 256];
  red[tid] = v0 + v1; __syncthreads();
  for (int s = 128; s; s >>= 1) { if (tid < s) red[tid] += red[tid + s]; __syncthreads(); }
  float mu = red[0] * (1.f / 512.f);
  __syncthreads();
  float d0 = v0 - mu, d1 = v1 - mu;
  red[tid] = d0 * d0 + d1 * d1; __syncthreads();
  for (int s = 128; s; s >>= 1) { if (tid < s) red[tid] += red[tid + s]; __syncthreads(); }
  float rstd = rsqrtf(red[0] * (1.f / 512.f) + 1e-5f);
  float* o = Outp + (size_t)row * 512;
  o[tid]       = d0 * rstd * gamma[tid]       + beta[tid];
  o[tid + 256] = d1 * rstd * gamma[tid + 256] + beta[tid + 256];
}

// ---------------------------------------------------------------------------
extern "C" void kernel_launch(void* const* d_in, const int* in_sizes, int n_in,
                              void* d_out, int out_size, void* d_ws, size_t ws_size,
                              hipStream_t stream) {
  const float* x     = (const float*)d_in[0];
  const float* Wq    = (const float*)d_in[1];
  const float* bq    = (const float*)d_in[2];
  const float* Wk    = (const float*)d_in[3];
  const float* bk    = (const float*)d_in[4];
  const float* Wv    = (const float*)d_in[5];
  const float* bv    = (const float*)d_in[6];
  const float* wpq   = (const float*)d_in[7];
  const float* wpk   = (const float*)d_in[8];
  const float* wpv   = (const float*)d_in[9];
  const float* wpx   = (const float*)d_in[10];
  const float* Wd    = (const float*)d_in[11];
  const float* bd    = (const float*)d_in[12];
  const float* gamma = (const float*)d_in[13];
  const float* beta  = (const float*)d_in[14];
  float* outp = (float*)d_out;

  auto rnd = [](size_t b) { return (b + 255) / 256 * 256; };
  const size_t persist =
      rnd((size_t)LP * 512 * 4) +            // embz
      rnd((size_t)Bb * Ll * 512 * 2) +       // xbf
      4 * rnd((size_t)512 * 2048 * 2) +      // wpxT + wpqT/wpkT/wpvT
      3 * rnd((size_t)8 * 512 * 512 * 2) +   // WqT/WkT/WvT
      rnd((size_t)512 * 4096 * 2) +          // WdB
      rnd((size_t)16 * LP * 512 * 2) +       // Outb
      rnd((size_t)2 * LP * 512 * 2) +        // PX
      rnd((size_t)2 * LL2 * 512 * 4) +       // Y
      rnd((size_t)16 * LP * 4);              // cfx
  auto chpart = [&](int CH) {
    return rnd((size_t)3 * CH * 512 * 2048 * 2) + rnd((size_t)3 * CH * 512 * 4) +
           3 * rnd((size_t)2 * CH * LP * 512 * 2);
  };
  const size_t lgbytes = rnd((size_t)LP * LP * 4);
  int CH = 8;
  while (CH > 1 && persist + chpart(CH) + lgbytes > ws_size) CH >>= 1;
  if (persist + chpart(CH) + lgbytes > ws_size) return;
  int NA = (int)((ws_size - persist - chpart(CH)) / lgbytes);
  if (NA > 2 * CH) NA = 2 * CH;
  int nc = 8 / CH;

  char* w = (char*)d_ws;
  auto alloc = [&](size_t bytes) { char* p = w; w += (bytes + 255) / 256 * 256; return p; };
  float* embz = (float*)alloc((size_t)LP * 512 * 4);
  short* xbf  = (short*)alloc((size_t)Bb * Ll * 512 * 2);
  short* wpxT = (short*)alloc((size_t)512 * 2048 * 2);
  short* wpqT = (short*)alloc((size_t)512 * 2048 * 2);
  short* wpkT = (short*)alloc((size_t)512 * 2048 * 2);
  short* wpvT = (short*)alloc((size_t)512 * 2048 * 2);
  short* WqT  = (short*)alloc((size_t)8 * 512 * 512 * 2);
  short* WkT  = (short*)alloc((size_t)8 * 512 * 512 * 2);
  short* WvT  = (short*)alloc((size_t)8 * 512 * 512 * 2);
  short* WdB  = (short*)alloc((size_t)512 * 4096 * 2);
  short* Outb = (short*)alloc((size_t)16 * LP * 512 * 2);
  short* PX   = (short*)alloc((size_t)2 * LP * 512 * 2);
  float* Y    = (float*)alloc((size_t)2 * LL2 * 512 * 4);
  float* cfx  = (float*)alloc((size_t)16 * LP * 4);
  short* Weff = (short*)alloc((size_t)3 * CH * 512 * 2048 * 2);
  float* beff = (float*)alloc((size_t)3 * CH * 512 * 4);
  short* PQ   = (short*)alloc((size_t)2 * CH * LP * 512 * 2);
  short* PKf  = (short*)alloc((size_t)2 * CH * LP * 512 * 2);
  short* PVt  = (short*)alloc((size_t)2 * CH * LP * 512 * 2);
  float* Lg   = (float*)alloc((size_t)NA * LP * LP * 4);

  dim3 blk(256);
  emb_kernel<<<dim3((LP * 512 + 255) / 256), blk, 0, stream>>>(embz);
  cvt_kernel<<<dim3((Bb * Ll * 512 / 4 + 255) / 256), blk, 0, stream>>>(x, xbf, Bb * Ll * 512 / 4);
  wpxt_kernel<<<dim3(4096), blk, 0, stream>>>(wpx, wpxT);
  wpxt_kernel<<<dim3(4096), blk, 0, stream>>>(wpq, wpqT);
  wpxt_kernel<<<dim3(4096), blk, 0, stream>>>(wpk, wpkT);
  wpxt_kernel<<<dim3(4096), blk, 0, stream>>>(wpv, wpvT);
  tr_w_kernel<<<dim3(8, 8, 8), blk, 0, stream>>>(Wq, WqT);
  tr_w_kernel<<<dim3(8, 8, 8), blk, 0, stream>>>(Wk, WkT);
  tr_w_kernel<<<dim3(8, 8, 8), blk, 0, stream>>>(Wv, WvT);
  cvt_kernel<<<dim3((512 * 4096 / 4 + 255) / 256), blk, 0, stream>>>(Wd, WdB, 512 * 4096 / 4);
  pxcls_kernel<<<dim3(2), dim3(512), 0, stream>>>(x, PX);

  for (int c = 0; c < nc; ++c) {
    int h0 = c * CH;
    weff128<<<dim3(4, 4, 12 * CH), blk, 0, stream>>>(wpqT, wpkT, wpvT, WqT, WkT, WvT,
                                                     h0, CH, Weff);
    beff_fused<<<dim3(3, CH, 4), blk, 0, stream>>>(bq, bk, bv, wpq, wpk, wpv, h0, CH, beff);
    pool128x2<<<dim3(13 * (12 * CH + 4)), blk, 0, stream>>>(xbf, Weff, wpxT, beff, embz,
                                                            PQ, PKf, PVt, PX, CH);
    cls_fast<<<dim3(128, 3, 2 * CH), blk, 0, stream>>>(xbf, Wq, bq, Wk, bk, Wv, bv,
                                                       h0, CH, PQ, PKf, PVt);
    for (int a0 = 0; a0 < 2 * CH; a0 += NA) {
      int na = (2 * CH - a0) < NA ? (2 * CH - a0) : NA;
      cfix_kernel<<<dim3(400, na), blk, 0, stream>>>(PQ, embz, a0, cfx);
      logits128<<<dim3(13, 13, na), blk, 0, stream>>>(PQ, PKf, cfx, a0, Lg);
      softmax_kernel<<<dim3((LL2 + 3) / 4, na), blk, 0, stream>>>(Lg);
      av128<<<dim3(13, 4, na), blk, 0, stream>>>(Lg, PVt, PQ, Outb, h0, CH, a0);
    }
  }

  final128<<<dim3(25, 4), blk, 0, stream>>>(Outb, WdB, bd, PX, Y);
  ln_kernel<<<dim3(Bb * LL2), blk, 0, stream>>>(Y, gamma, beta, outp);
}